// Round 2
// baseline (647.125 us; speedup 1.0000x reference)
//
#include <hip/hip_runtime.h>
#include <hip/hip_bf16.h>

typedef __hip_bfloat16 bf16;
typedef __attribute__((ext_vector_type(8))) unsigned short u16x8;
typedef __attribute__((ext_vector_type(4))) float f32x4;

#define B_   64
#define NE_  256
#define NN_  1024
#define L_   512
#define HID_ 128
#define ALPHA_ 0.2f

__device__ __forceinline__ float bfu(unsigned short u){
  unsigned int x = ((unsigned int)u) << 16;
  union { unsigned int i; float f; } c; c.i = x; return c.f;
}
__device__ __forceinline__ unsigned short f2b(float f){
  bf16 h = __float2bfloat16(f);
  union { bf16 b; unsigned short u; } c; c.b = h; return c.u;
}

// consts layout (floats): [0:128) ce1_1, [128:256) cf1_1, [256:384) cf2_1,
// [384:512) ce1_2, [512:640) cf1_2, [640:768) cf2_2, [768] s0_1, [769] s0_2
__global__ void k_consts(const float* w2_1, const float* w3_1,
                         const float* a_1, const float* a2_1, const float* wc_1,
                         const float* w2_2, const float* w3_2,
                         const float* a_2, const float* a2_2, const float* wc_2,
                         const float* w_2,
                         float* consts, unsigned short* W2B)
{
  int blk = blockIdx.x, t = threadIdx.x; // 128 threads
  __shared__ float red[128];
  if (blk < 6) {
    const float* M; const float* v;
    switch (blk) {
      case 0: M = w2_1; v = a_1  + 128; break;
      case 1: M = w2_1; v = a2_1;       break;
      case 2: M = w3_1; v = a2_1 + 128; break;
      case 3: M = w2_2; v = a_2  + 128; break;
      case 4: M = w2_2; v = a2_2;       break;
      default: M = w3_2; v = a2_2 + 128; break;
    }
    float acc = 0.f;
    for (int o = 0; o < 128; ++o) acc += M[t*128 + o] * v[o];
    consts[blk*128 + t] = acc;
  } else if (blk < 8) {
    const float* wc = (blk == 6) ? wc_1 : wc_2;
    const float* a  = (blk == 6) ? a_1  : a_2;
    red[t] = wc[t] * a[t];
    __syncthreads();
    for (int s = 64; s > 0; s >>= 1) { if (t < s) red[t] += red[t + s]; __syncthreads(); }
    if (t == 0) consts[768 + (blk - 6)] = red[0];
  } else {
    for (int o = 0; o < 128; ++o) W2B[t*128 + o] = f2b(w_2[t*128 + o]);
  }
}

// adjT[b][n][e] = bf16(adj[b][e][n])
__global__ void k_adjT(const float* __restrict__ adj, unsigned short* __restrict__ adjT)
{
  __shared__ unsigned short tile[64][65];
  int b  = blockIdx.z;
  int e0 = blockIdx.y * 64;
  int n0 = blockIdx.x * 64;
  int t  = threadIdx.x;                 // 256
  int lr = t >> 2, lc0 = (t & 3) * 16;
  const float* src = adj + ((long)b*NE_ + e0 + lr)*NN_ + n0 + lc0;
  #pragma unroll
  for (int j = 0; j < 16; j += 4) {
    f32x4 v = *(const f32x4*)(src + j);
    tile[lr][lc0 + j + 0] = f2b(v[0]);
    tile[lr][lc0 + j + 1] = f2b(v[1]);
    tile[lr][lc0 + j + 2] = f2b(v[2]);
    tile[lr][lc0 + j + 3] = f2b(v[3]);
  }
  __syncthreads();
  u16x8 o0, o1;
  #pragma unroll
  for (int j = 0; j < 8; ++j) o0[j] = tile[lc0 + j][lr];
  #pragma unroll
  for (int j = 0; j < 8; ++j) o1[j] = tile[lc0 + 8 + j][lr];
  unsigned short* dst = adjT + ((long)b*NN_ + n0 + lr)*NE_ + e0 + lc0;
  *(u16x8*)dst = o0;
  *(u16x8*)(dst + 8) = o1;
}

// e1[r] = leaky(x_row . ce1 + s0); f1[r] = x_row . cf1   (wave per row)
__global__ void k_proj(const float* __restrict__ srcF, const unsigned short* __restrict__ srcBF,
                       const int* __restrict__ gitems,
                       const float* __restrict__ consts, int layer,
                       float* __restrict__ e1, float* __restrict__ f1)
{
  int t = threadIdx.x;                    // 256 = 4 waves
  int wv = t >> 6, lane = t & 63;
  long row = (long)blockIdx.x * 4 + wv;
  const float* ce1 = consts + layer * 384;
  const float* cf1 = ce1 + 128;
  float s0 = consts[768 + layer];
  long base = gitems ? (long)gitems[row] * HID_ : row * HID_;
  float v0, v1;
  if (srcF) { v0 = srcF[base + lane]; v1 = srcF[base + lane + 64]; }
  else      { v0 = bfu(srcBF[base + lane]); v1 = bfu(srcBF[base + lane + 64]); }
  float p1 = v0 * ce1[lane] + v1 * ce1[lane + 64];
  float p2 = v0 * cf1[lane] + v1 * cf1[lane + 64];
  #pragma unroll
  for (int s = 32; s > 0; s >>= 1) { p1 += __shfl_xor(p1, s); p2 += __shfl_xor(p2, s); }
  if (lane == 0) {
    float z = p1 + s0;
    e1[row] = (z >= 0.f) ? z : ALPHA_ * z;
    f1[row] = p2;
  }
}

__global__ void k_bmax(const float* __restrict__ e1, const float* __restrict__ f1,
                       float* __restrict__ M1, float* __restrict__ Mf1)
{
  int b = blockIdx.x, t = threadIdx.x;    // 256
  float m1 = -1e30f, m2 = -1e30f;
  for (int i = t; i < NN_; i += 256) {
    m1 = fmaxf(m1, e1[b*NN_ + i]);
    m2 = fmaxf(m2, f1[b*NN_ + i]);
  }
  __shared__ float s1[256], s2[256];
  s1[t] = m1; s2[t] = m2; __syncthreads();
  for (int s = 128; s > 0; s >>= 1) {
    if (t < s) { s1[t] = fmaxf(s1[t], s1[t+s]); s2[t] = fmaxf(s2[t], s2[t+s]); }
    __syncthreads();
  }
  if (t == 0) { M1[b] = s1[0]; Mf1[b] = s2[0]; }
}

// w1[r] = exp(e1[r]-M1[b]); Y[r][h] = bf16(w1 * x[r][h])
__global__ void k_w1y(const float* __restrict__ e1, const float* __restrict__ M1,
                      const float* __restrict__ src, const int* __restrict__ gitems,
                      float* __restrict__ w1, bf16* __restrict__ Y)
{
  long total = (long)B_*NN_*HID_;
  long i = (long)blockIdx.x * blockDim.x + threadIdx.x;
  long stride = (long)gridDim.x * blockDim.x;
  for (; i < total; i += stride) {
    long r = i >> 7; int h = (int)(i & 127);
    int b = (int)(r >> 10);
    float w = expf(e1[r] - M1[b]);
    float x = gitems ? src[(long)gitems[r]*HID_ + h] : src[i];
    Y[i] = __float2bfloat16(w * x);
    if (h == 0) w1[r] = w;
  }
}

// den1[b][e] = adj[b][e][:] . w1[b][:]   (wave per row, f32 adj)
__global__ void k_den1(const float* __restrict__ adj, const float* __restrict__ w1,
                       float* __restrict__ den1)
{
  int t = threadIdx.x; int wv = t >> 6, lane = t & 63;
  long idx = (long)blockIdx.x * 4 + wv;     // b*NE+e
  int b = (int)(idx >> 8);
  const float* ar = adj + idx * NN_;
  const float* wr = w1 + (long)b * NN_;
  float acc = 0.f;
  for (int i = lane; i < NN_; i += 64) acc += ar[i] * wr[i];
  #pragma unroll
  for (int s = 32; s > 0; s >>= 1) acc += __shfl_xor(acc, s);
  if (lane == 0) den1[idx] = acc;
}

#define TM 64
#define KC 32
// C[M x 128] = A[M x K] @ B[K x 128](bf16), f32 accumulate. AF32: A is f32 else bf16.
// EPI 0: f32 C (K-split partials via kz*psC); 1: div by den -> f32 C; 2: div+elu -> bf16 Cbf
template<int EPI, int AF32>
__global__ __launch_bounds__(256) void k_gemm(
    const void* __restrict__ A, long sA, int lda,
    const unsigned short* __restrict__ Bm, long sB,
    float* __restrict__ C, long sC,
    bf16* __restrict__ Cbf, long sCbf,
    const float* __restrict__ den, int sden,
    int ksplit, long psC)
{
  __shared__ float As[KC][TM];
  __shared__ float Bs[KC][HID_];
  int batch = blockIdx.y;
  int m0 = blockIdx.x * TM;
  int kz = blockIdx.z;
  int t = threadIdx.x;
  const unsigned short* Bb = Bm + (long)batch * sB;
  float acc[2][16];
  #pragma unroll
  for (int i = 0; i < 16; ++i) { acc[0][i] = 0.f; acc[1][i] = 0.f; }
  int mp = t >> 3;                 // 0..31
  int h0 = (t & 7) * 16;
  int ar = t >> 2, ak = (t & 3) * 8;
  int bk = t >> 3, bc = (t & 7) * 16;
  int kend = kz * ksplit + ksplit;
  for (int kc = kz * ksplit; kc < kend; kc += KC) {
    float af[8];
    if (AF32) {
      const float* Ap = (const float*)A + (long)batch*sA + (long)(m0 + ar)*lda + kc + ak;
      f32x4 x0 = *(const f32x4*)Ap;
      f32x4 x1 = *(const f32x4*)(Ap + 4);
      #pragma unroll
      for (int j = 0; j < 4; ++j) { af[j] = x0[j]; af[4+j] = x1[j]; }
    } else {
      const unsigned short* Ap = (const unsigned short*)A + (long)batch*sA + (long)(m0 + ar)*lda + kc + ak;
      u16x8 av = *(const u16x8*)Ap;
      #pragma unroll
      for (int j = 0; j < 8; ++j) af[j] = bfu(av[j]);
    }
    u16x8 bv0 = *(const u16x8*)(Bb + (long)(kc + bk) * HID_ + bc);
    u16x8 bv1 = *(const u16x8*)(Bb + (long)(kc + bk) * HID_ + bc + 8);
    #pragma unroll
    for (int j = 0; j < 8; ++j) As[ak + j][ar] = af[j];
    #pragma unroll
    for (int j = 0; j < 8; ++j) Bs[bk][bc + j] = bfu(bv0[j]);
    #pragma unroll
    for (int j = 0; j < 8; ++j) Bs[bk][bc + 8 + j] = bfu(bv1[j]);
    __syncthreads();
    #pragma unroll 4
    for (int kk = 0; kk < KC; ++kk) {
      float a0 = As[kk][2*mp];
      float a1 = As[kk][2*mp + 1];
      #pragma unroll
      for (int i = 0; i < 16; ++i) {
        float bv = Bs[kk][h0 + i];
        acc[0][i] += a0 * bv;
        acc[1][i] += a1 * bv;
      }
    }
    __syncthreads();
  }
  #pragma unroll
  for (int rr = 0; rr < 2; ++rr) {
    int row = m0 + 2*mp + rr;
    float d = 1.f;
    if (EPI >= 1) d = 1.f / den[(long)batch * sden + row];
    if (EPI == 2) {
      bf16* cb = Cbf + (long)batch * sCbf + (long)row * HID_ + h0;
      #pragma unroll
      for (int i = 0; i < 16; ++i) {
        float v = acc[rr][i] * d;
        v = (v > 0.f) ? v : expm1f(v);
        cb[i] = __float2bfloat16(v);
      }
    } else {
      float* cp = C + kz * psC + (long)batch * sC + (long)row * HID_ + h0;
      #pragma unroll
      for (int i = 0; i < 16; ++i) cp[i] = acc[rr][i] * d;
    }
  }
}

// edge = (num0+num1)/den1 -> bf16 EBF; f2[r] = edge_row . cf2
__global__ void k_edge_fin(const float* __restrict__ num, const float* __restrict__ den1,
                           const float* __restrict__ consts, int layer,
                           bf16* __restrict__ ebf, float* __restrict__ f2)
{
  long r = blockIdx.x; int t = threadIdx.x;   // 128 threads
  const float* cf2 = consts + layer * 384 + 256;
  float d = 1.f / den1[r];
  long pstride = (long)B_ * NE_ * HID_;
  float v = (num[r*HID_ + t] + num[pstride + r*HID_ + t]) * d;
  ebf[r*HID_ + t] = __float2bfloat16(v);
  float p = v * cf2[t];
  int lane = t & 63;
  #pragma unroll
  for (int s = 32; s > 0; s >>= 1) p += __shfl_xor(p, s);
  __shared__ float sr[2];
  if (lane == 0) sr[t >> 6] = p;
  __syncthreads();
  if (t == 0) f2[r] = sr[0] + sr[1];
}

__global__ void k_maxf2(const float* __restrict__ f2, const float* __restrict__ Mf1,
                        float* __restrict__ C2)
{
  int b = blockIdx.x, t = threadIdx.x;  // 256
  __shared__ float s1[256];
  s1[t] = f2[b*NE_ + t]; __syncthreads();
  for (int s = 128; s > 0; s >>= 1) { if (t < s) s1[t] = fmaxf(s1[t], s1[t+s]); __syncthreads(); }
  if (t == 0) { float z = Mf1[b] + s1[0]; C2[b] = (z >= 0.f) ? z : ALPHA_ * z; }
}

// A2[b][n][e] = mask ? exp(leaky(f1+f2)-C2) : 0 (bf16); den2[b][n] = sum_e
__global__ void k_att(const unsigned short* __restrict__ adjT, const float* __restrict__ f1,
                      const float* __restrict__ f2, const float* __restrict__ C2,
                      bf16* __restrict__ A2, float* __restrict__ den2)
{
  long r = blockIdx.x; int t = threadIdx.x;   // 256 threads = e
  int b = (int)(r >> 10);
  float m = bfu(adjT[r*NE_ + t]);
  float z = f1[r] + f2[b*NE_ + t];
  z = (z >= 0.f) ? z : ALPHA_ * z;
  float w = (m > 0.f) ? expf(z - C2[b]) : 0.f;
  bf16 wb = __float2bfloat16(w);
  A2[r*NE_ + t] = wb;
  float ws = bfu(*(unsigned short*)&wb);
  int lane = t & 63;
  #pragma unroll
  for (int s = 32; s > 0; s >>= 1) ws += __shfl_xor(ws, s);
  __shared__ float sr[4];
  if (lane == 0) sr[t >> 6] = ws;
  __syncthreads();
  if (t == 0) den2[r] = sr[0] + sr[1] + sr[2] + sr[3];
}

__global__ void k_pool(const int* __restrict__ alias, const float* __restrict__ masks,
                       const float* __restrict__ X3, const float* __restrict__ ln_g,
                       const float* __restrict__ ln_b, float* __restrict__ out)
{
  int b = blockIdx.x, t = threadIdx.x;   // 128
  float acc = 0.f, msum = 0.f;
  for (int l = 0; l < L_; ++l) {
    float mv = masks[b*L_ + l];
    int idx  = alias[b*L_ + l];
    acc  += mv * mv * X3[((long)b*NN_ + idx)*HID_ + t];
    msum += mv;
  }
  float bv = acc / msum;
  __shared__ float sr[2];
  int lane = t & 63;
  float p = bv;
  #pragma unroll
  for (int s = 32; s > 0; s >>= 1) p += __shfl_xor(p, s);
  if (lane == 0) sr[t >> 6] = p;
  __syncthreads();
  float mu = (sr[0] + sr[1]) * (1.f / HID_);
  float dv = bv - mu;
  p = dv * dv;
  #pragma unroll
  for (int s = 32; s > 0; s >>= 1) p += __shfl_xor(p, s);
  __syncthreads();
  if (lane == 0) sr[t >> 6] = p;
  __syncthreads();
  float var = (sr[0] + sr[1]) * (1.f / HID_);
  float o = dv / sqrtf(var + 1e-6f) * ln_g[t] + ln_b[t];
  out[b*HID_ + t] = o;
}

extern "C" void kernel_launch(void* const* d_in, const int* in_sizes, int n_in,
                              void* d_out, int out_size, void* d_ws, size_t ws_size,
                              hipStream_t stream)
{
  const int*   items = (const int*)d_in[0];
  const int*   alias = (const int*)d_in[1];
  const float* masks = (const float*)d_in[2];
  const float* adj   = (const float*)d_in[3];
  const float* emb   = (const float*)d_in[4];
  const float* w2_1  = (const float*)d_in[5];
  const float* w3_1  = (const float*)d_in[6];
  const float* a_1   = (const float*)d_in[7];
  const float* a2_1  = (const float*)d_in[8];
  const float* wc_1  = (const float*)d_in[9];
  const float* w_2   = (const float*)d_in[10];
  const float* w2_2  = (const float*)d_in[11];
  const float* w3_2  = (const float*)d_in[12];
  const float* a_2   = (const float*)d_in[13];
  const float* a2_2  = (const float*)d_in[14];
  const float* wc_2  = (const float*)d_in[15];
  const float* ln_g  = (const float*)d_in[16];
  const float* ln_b  = (const float*)d_in[17];
  float* out = (float*)d_out;

  char* ws = (char*)d_ws;
  size_t off = 0;
  auto alloc = [&](size_t bytes) -> void* {
    void* p = ws + off; off += (bytes + 255) / 256 * 256; return p;
  };
  float* X1    = (float*)alloc((size_t)B_*NN_*HID_*4);   // aliases: ENUM0 / XW / X3
  bf16*  YBF   = (bf16*) alloc((size_t)B_*NN_*HID_*2);
  bf16*  X2BF  = (bf16*) alloc((size_t)B_*NN_*HID_*2);
  bf16*  ADJT  = (bf16*) alloc((size_t)B_*NN_*NE_*2);
  bf16*  A2BF  = (bf16*) alloc((size_t)B_*NN_*NE_*2);
  bf16*  EBF   = (bf16*) alloc((size_t)B_*NE_*HID_*2);
  float* e1    = (float*)alloc((size_t)B_*NN_*4);
  float* f1    = (float*)alloc((size_t)B_*NN_*4);
  float* w1    = (float*)alloc((size_t)B_*NN_*4);
  float* den2  = (float*)alloc((size_t)B_*NN_*4);
  float* den1  = (float*)alloc((size_t)B_*NE_*4);
  float* f2    = (float*)alloc((size_t)B_*NE_*4);
  float* M1    = (float*)alloc(B_*4);
  float* Mf1   = (float*)alloc(B_*4);
  float* C2    = (float*)alloc(B_*4);
  float* consts= (float*)alloc(772*4);
  unsigned short* W2B = (unsigned short*)alloc((size_t)HID_*HID_*2);
  if (off > ws_size) return;   // workspace insufficient -> fail visibly

  float* ENUM0 = X1;   // 16.8 MB, lifetime disjoint from XW/X3 uses of X1

  const long sAdj = (long)NE_*NN_, sY = (long)NN_*HID_, sE = (long)NE_*HID_;
  const long sA2 = (long)NN_*NE_;
  const long psC = (long)B_*NE_*HID_;

  k_consts<<<9, 128, 0, stream>>>(w2_1, w3_1, a_1, a2_1, wc_1, w2_2, w3_2, a_2, a2_2, wc_2,
                                  w_2, consts, W2B);
  k_adjT<<<dim3(NN_/64, NE_/64, B_), 256, 0, stream>>>(adj, (unsigned short*)ADJT);

  // ---------------- layer 1 ----------------
  k_proj<<<B_*NN_/4, 256, 0, stream>>>(emb, nullptr, items, consts, 0, e1, f1);
  k_bmax<<<B_, 256, 0, stream>>>(e1, f1, M1, Mf1);
  k_w1y<<<2048, 256, 0, stream>>>(e1, M1, emb, items, w1, YBF);
  k_den1<<<B_*NE_/4, 256, 0, stream>>>(adj, w1, den1);
  k_gemm<0,1><<<dim3(NE_/TM, B_, 2), 256, 0, stream>>>(adj, sAdj, NN_,
        (const unsigned short*)YBF, sY, ENUM0, sE, nullptr, 0, nullptr, 0,
        NN_/2, psC);
  k_edge_fin<<<B_*NE_, 128, 0, stream>>>(ENUM0, den1, consts, 0, EBF, f2);
  k_maxf2<<<B_, 256, 0, stream>>>(f2, Mf1, C2);
  k_att<<<B_*NN_, 256, 0, stream>>>((const unsigned short*)ADJT, f1, f2, C2, A2BF, den2);
  k_gemm<2,0><<<dim3(NN_/TM, B_, 1), 256, 0, stream>>>((const unsigned short*)A2BF, sA2, NE_,
        (const unsigned short*)EBF, sE, nullptr, 0, X2BF, sY, den2, NN_,
        NE_, 0);

  // ---------------- layer 2 ----------------
  k_proj<<<B_*NN_/4, 256, 0, stream>>>(nullptr, (const unsigned short*)X2BF, nullptr, consts, 1, e1, f1);
  k_bmax<<<B_, 256, 0, stream>>>(e1, f1, M1, Mf1);
  k_gemm<0,0><<<dim3(NN_/TM, B_, 1), 256, 0, stream>>>((const unsigned short*)X2BF, sY, HID_,
        W2B, 0, X1 /*XW*/, sY, nullptr, 0, nullptr, 0,
        HID_, 0);
  k_w1y<<<2048, 256, 0, stream>>>(e1, M1, X1 /*XW*/, nullptr, w1, YBF);
  k_den1<<<B_*NE_/4, 256, 0, stream>>>(adj, w1, den1);
  k_gemm<0,1><<<dim3(NE_/TM, B_, 2), 256, 0, stream>>>(adj, sAdj, NN_,
        (const unsigned short*)YBF, sY, ENUM0, sE, nullptr, 0, nullptr, 0,
        NN_/2, psC);
  k_edge_fin<<<B_*NE_, 128, 0, stream>>>(ENUM0, den1, consts, 1, EBF, f2);
  k_maxf2<<<B_, 256, 0, stream>>>(f2, Mf1, C2);
  k_att<<<B_*NN_, 256, 0, stream>>>((const unsigned short*)ADJT, f1, f2, C2, A2BF, den2);
  k_gemm<1,0><<<dim3(NN_/TM, B_, 1), 256, 0, stream>>>((const unsigned short*)A2BF, sA2, NE_,
        (const unsigned short*)EBF, sE, X1 /*X3*/, sY, nullptr, 0, den2, NN_,
        NE_, 0);

  // ---------------- pool + layernorm ----------------
  k_pool<<<B_, 128, 0, stream>>>(alias, masks, X1 /*X3*/, ln_g, ln_b, out);
}

// Round 3
// 232.398 us; speedup vs baseline: 2.7846x; 2.7846x over previous
//
#include <hip/hip_runtime.h>
#include <hip/hip_bf16.h>

typedef __hip_bfloat16 bf16;
typedef __attribute__((ext_vector_type(8))) unsigned short u16x8;
typedef __attribute__((ext_vector_type(4))) unsigned short u16x4;
typedef __attribute__((ext_vector_type(4))) float f32x4;
typedef __attribute__((ext_vector_type(8))) short bf16x8;

#define B_   64
#define NE_  256
#define NN_  1024
#define L_   512
#define HID_ 128
#define ALPHA_ 0.2f

__device__ __forceinline__ float bfu(unsigned short u){
  unsigned int x = ((unsigned int)u) << 16;
  union { unsigned int i; float f; } c; c.i = x; return c.f;
}
__device__ __forceinline__ unsigned short f2b(float f){
  bf16 h = __float2bfloat16(f);
  union { bf16 b; unsigned short u; } c; c.b = h; return c.u;
}
// chunk swizzle: involution in c for fixed r; spreads frag reads to 2-way max
__device__ __forceinline__ int swz(int r, int c){ return (c ^ (r & 3) ^ ((r >> 2) & 3)) & 3; }

// consts layout (floats): [0:128) ce1_1, [128:256) cf1_1, [256:384) cf2_1,
// [384:512) ce1_2, [512:640) cf1_2, [640:768) cf2_2, [768] s0_1, [769] s0_2
__global__ void k_consts(const float* w2_1, const float* w3_1,
                         const float* a_1, const float* a2_1, const float* wc_1,
                         const float* w2_2, const float* w3_2,
                         const float* a_2, const float* a2_2, const float* wc_2,
                         const float* w_2,
                         float* consts, unsigned short* W2T)
{
  int blk = blockIdx.x, t = threadIdx.x; // 128 threads
  __shared__ float red[128];
  if (blk < 6) {
    const float* M; const float* v;
    switch (blk) {
      case 0: M = w2_1; v = a_1  + 128; break;
      case 1: M = w2_1; v = a2_1;       break;
      case 2: M = w3_1; v = a2_1 + 128; break;
      case 3: M = w2_2; v = a_2  + 128; break;
      case 4: M = w2_2; v = a2_2;       break;
      default: M = w3_2; v = a2_2 + 128; break;
    }
    float acc = 0.f;
    for (int o = 0; o < 128; ++o) acc += M[t*128 + o] * v[o];
    consts[blk*128 + t] = acc;
  } else if (blk < 8) {
    const float* wc = (blk == 6) ? wc_1 : wc_2;
    const float* a  = (blk == 6) ? a_1  : a_2;
    red[t] = wc[t] * a[t];
    __syncthreads();
    for (int s = 64; s > 0; s >>= 1) { if (t < s) red[t] += red[t + s]; __syncthreads(); }
    if (t == 0) consts[768 + (blk - 6)] = red[0];
  } else {
    // W2T[h][k] = w_2[k][h]
    for (int k = 0; k < 128; ++k) W2T[t*128 + k] = f2b(w_2[k*128 + t]);
  }
}

// adjT[b][n][e] = bf16(adj[b][e][n])
__global__ void k_adjT(const float* __restrict__ adj, unsigned short* __restrict__ adjT)
{
  __shared__ unsigned short tile[64][65];
  int b  = blockIdx.z;
  int e0 = blockIdx.y * 64;
  int n0 = blockIdx.x * 64;
  int t  = threadIdx.x;                 // 256
  int lr = t >> 2, lc0 = (t & 3) * 16;
  const float* src = adj + ((long)b*NE_ + e0 + lr)*NN_ + n0 + lc0;
  #pragma unroll
  for (int j = 0; j < 16; j += 4) {
    f32x4 v = *(const f32x4*)(src + j);
    tile[lr][lc0 + j + 0] = f2b(v[0]);
    tile[lr][lc0 + j + 1] = f2b(v[1]);
    tile[lr][lc0 + j + 2] = f2b(v[2]);
    tile[lr][lc0 + j + 3] = f2b(v[3]);
  }
  __syncthreads();
  u16x8 o0, o1;
  #pragma unroll
  for (int j = 0; j < 8; ++j) o0[j] = tile[lc0 + j][lr];
  #pragma unroll
  for (int j = 0; j < 8; ++j) o1[j] = tile[lc0 + 8 + j][lr];
  unsigned short* dst = adjT + ((long)b*NN_ + n0 + lr)*NE_ + e0 + lc0;
  *(u16x8*)dst = o0;
  *(u16x8*)(dst + 8) = o1;
}

// e1[r] = leaky(x_row . ce1 + s0); f1[r] = x_row . cf1   (wave per row)
__global__ void k_proj(const float* __restrict__ srcF, const unsigned short* __restrict__ srcBF,
                       const int* __restrict__ gitems,
                       const float* __restrict__ consts, int layer,
                       float* __restrict__ e1, float* __restrict__ f1)
{
  int t = threadIdx.x;                    // 256 = 4 waves
  int wv = t >> 6, lane = t & 63;
  long row = (long)blockIdx.x * 4 + wv;
  const float* ce1 = consts + layer * 384;
  const float* cf1 = ce1 + 128;
  float s0 = consts[768 + layer];
  long base = gitems ? (long)gitems[row] * HID_ : row * HID_;
  float v0, v1;
  if (srcF) { v0 = srcF[base + lane]; v1 = srcF[base + lane + 64]; }
  else      { v0 = bfu(srcBF[base + lane]); v1 = bfu(srcBF[base + lane + 64]); }
  float p1 = v0 * ce1[lane] + v1 * ce1[lane + 64];
  float p2 = v0 * cf1[lane] + v1 * cf1[lane + 64];
  #pragma unroll
  for (int s = 32; s > 0; s >>= 1) { p1 += __shfl_xor(p1, s); p2 += __shfl_xor(p2, s); }
  if (lane == 0) {
    float z = p1 + s0;
    e1[row] = (z >= 0.f) ? z : ALPHA_ * z;
    f1[row] = p2;
  }
}

__global__ void k_bmax(const float* __restrict__ e1, const float* __restrict__ f1,
                       float* __restrict__ M1, float* __restrict__ Mf1)
{
  int b = blockIdx.x, t = threadIdx.x;    // 256
  float m1 = -1e30f, m2 = -1e30f;
  for (int i = t; i < NN_; i += 256) {
    m1 = fmaxf(m1, e1[b*NN_ + i]);
    m2 = fmaxf(m2, f1[b*NN_ + i]);
  }
  __shared__ float s1[256], s2[256];
  s1[t] = m1; s2[t] = m2; __syncthreads();
  for (int s = 128; s > 0; s >>= 1) {
    if (t < s) { s1[t] = fmaxf(s1[t], s1[t+s]); s2[t] = fmaxf(s2[t], s2[t+s]); }
    __syncthreads();
  }
  if (t == 0) { M1[b] = s1[0]; Mf1[b] = s2[0]; }
}

// w1[row]=exp(e1-M1); YT[b][h][n] = bf16(w1 * x[row][h])  (transposed output)
template<int SRCBF>
__global__ void k_w1y(const float* __restrict__ e1, const float* __restrict__ M1,
                      const float* __restrict__ srcF, const unsigned short* __restrict__ srcB,
                      const int* __restrict__ gitems,
                      float* __restrict__ w1, unsigned short* __restrict__ YT)
{
  __shared__ __attribute__((aligned(16))) unsigned short T[64][132];
  int b = blockIdx.y, n0 = blockIdx.x * 64, t = threadIdx.x;  // 256
  int r = t >> 2, h0 = (t & 3) * 32;
  long row = (long)b*NN_ + n0 + r;
  float wgt = __expf(e1[row] - M1[b]);
  if ((t & 3) == 0) w1[row] = wgt;
  long base = gitems ? (long)gitems[row] * HID_ : row * HID_;
  if (SRCBF) {
    #pragma unroll
    for (int j = 0; j < 32; j += 8) {
      u16x8 xv = *(const u16x8*)(srcB + base + h0 + j);
      u16x4 o0, o1;
      #pragma unroll
      for (int k2 = 0; k2 < 4; ++k2) { o0[k2] = f2b(wgt*bfu(xv[k2])); o1[k2] = f2b(wgt*bfu(xv[4+k2])); }
      *(u16x4*)&T[r][h0+j]   = o0;
      *(u16x4*)&T[r][h0+j+4] = o1;
    }
  } else {
    #pragma unroll
    for (int j = 0; j < 32; j += 4) {
      f32x4 xv = *(const f32x4*)(srcF + base + h0 + j);
      u16x4 o;
      #pragma unroll
      for (int k2 = 0; k2 < 4; ++k2) o[k2] = f2b(wgt*xv[k2]);
      *(u16x4*)&T[r][h0+j] = o;
    }
  }
  __syncthreads();
  int h = t >> 1, nh = (t & 1) * 32;
  unsigned short* dst = YT + ((long)b*HID_ + h)*NN_ + n0 + nh;
  #pragma unroll
  for (int j = 0; j < 32; j += 8) {
    u16x8 o;
    #pragma unroll
    for (int k2 = 0; k2 < 8; ++k2) o[k2] = T[nh+j+k2][h];
    *(u16x8*)&dst[j] = o;
  }
}

// ---------------- MFMA GEMM: C[Mx128] = A[MxK] @ BT[128xK]^T ----------------
// ASRC: 0 = adj f32 (+den1 dot w/ w1), 1 = fused attention from ADJT, 2 = plain bf16
// EPI : 0 = f32 out + den1 store, 1 = /dsum + elu -> bf16, 2 = /dsum -> f32, 3 = bf16 out
template<int ASRC, int EPI>
__global__ __launch_bounds__(256) void k_mgemm(
    const void* __restrict__ Aav, long sA, int lda,
    const unsigned short* __restrict__ Bt, long sB, int K,
    float* __restrict__ Cf, unsigned short* __restrict__ Cb, long sC,
    const float* __restrict__ w1v, float* __restrict__ den1o,
    const float* __restrict__ f1v, const float* __restrict__ f2v,
    const float* __restrict__ C2v)
{
  __shared__ __attribute__((aligned(16))) unsigned short As[64*32];
  __shared__ __attribute__((aligned(16))) unsigned short Bs[128*32];
  __shared__ float dsum[64];
  const int b = blockIdx.y;
  const long m0 = (long)blockIdx.x * 64;
  const int t = threadIdx.x;
  const int lane = t & 63;
  const int w = t >> 6, wm = w >> 1, wn = w & 1;
  const int r4 = t >> 2, c4 = t & 3;
  const int lr = lane & 15, g = lane >> 4;

  f32x4 acc[2][4];
  #pragma unroll
  for (int i = 0; i < 2; ++i)
    #pragma unroll
    for (int j = 0; j < 4; ++j) acc[i][j] = (f32x4){0.f,0.f,0.f,0.f};

  if ((ASRC == 0 || ASRC == 1) && (t & 3) == 0) dsum[r4] = 0.f;

  float f1r = 0.f, c2s = 0.f;
  if (ASRC == 1) { f1r = f1v[(long)b*NN_ + m0 + r4]; c2s = C2v[b]; }

  const unsigned short* Bb = Bt + (long)b * sB;

  for (int kc = 0; kc < K; kc += 32) {
    if (kc) __syncthreads();
    // ---- stage A ----
    if (ASRC == 0) {
      const float* Ap = (const float*)Aav + (long)b*sA + (m0 + r4)*(long)lda + kc + c4*8;
      f32x4 x0 = *(const f32x4*)Ap;
      f32x4 x1 = *(const f32x4*)(Ap + 4);
      const float* wp = w1v + (long)b*NN_ + kc + c4*8;
      f32x4 w0 = *(const f32x4*)wp;
      f32x4 w1x = *(const f32x4*)(wp + 4);
      float dot = x0[0]*w0[0]+x0[1]*w0[1]+x0[2]*w0[2]+x0[3]*w0[3]
                + x1[0]*w1x[0]+x1[1]*w1x[1]+x1[2]*w1x[2]+x1[3]*w1x[3];
      u16x8 av;
      #pragma unroll
      for (int j = 0; j < 4; ++j) { av[j] = f2b(x0[j]); av[4+j] = f2b(x1[j]); }
      *(u16x8*)&As[r4*32 + swz(r4,c4)*8] = av;
      dot += __shfl_down(dot, 2, 4); dot += __shfl_down(dot, 1, 4);
      if ((lane & 3) == 0) dsum[r4] += dot;
    } else if (ASRC == 1) {
      const unsigned short* Ap = (const unsigned short*)Aav + (long)b*sA + (m0 + r4)*(long)lda + kc + c4*8;
      u16x8 mv = *(const u16x8*)Ap;
      const float* f2p = f2v + (long)b*NE_ + kc + c4*8;
      f32x4 f20 = *(const f32x4*)f2p;
      f32x4 f21 = *(const f32x4*)(f2p + 4);
      float fv[8] = {f20[0],f20[1],f20[2],f20[3],f21[0],f21[1],f21[2],f21[3]};
      u16x8 av; float dot = 0.f;
      #pragma unroll
      for (int j = 0; j < 8; ++j) {
        float z = f1r + fv[j];
        z = (z >= 0.f) ? z : ALPHA_ * z;
        float wt = (bfu(mv[j]) > 0.f) ? __expf(z - c2s) : 0.f;
        unsigned short ub = f2b(wt);
        av[j] = ub; dot += bfu(ub);
      }
      *(u16x8*)&As[r4*32 + swz(r4,c4)*8] = av;
      dot += __shfl_down(dot, 2, 4); dot += __shfl_down(dot, 1, 4);
      if ((lane & 3) == 0) dsum[r4] += dot;
    } else {
      const unsigned short* Ap = (const unsigned short*)Aav + (long)b*sA + (m0 + r4)*(long)lda + kc + c4*8;
      u16x8 av = *(const u16x8*)Ap;
      *(u16x8*)&As[r4*32 + swz(r4,c4)*8] = av;
    }
    // ---- stage B ----
    #pragma unroll
    for (int jj = 0; jj < 2; ++jj) {
      int rB = jj*64 + r4;
      u16x8 bv = *(const u16x8*)(Bb + (long)rB*K + kc + c4*8);
      *(u16x8*)&Bs[rB*32 + swz(rB,c4)*8] = bv;
    }
    __syncthreads();
    // ---- compute ----
    bf16x8 af[2], bfr[4];
    #pragma unroll
    for (int mt = 0; mt < 2; ++mt) {
      int r = wm*32 + mt*16 + lr;
      af[mt] = *(const bf16x8*)&As[r*32 + swz(r,g)*8];
    }
    #pragma unroll
    for (int nt = 0; nt < 4; ++nt) {
      int n = wn*64 + nt*16 + lr;
      bfr[nt] = *(const bf16x8*)&Bs[n*32 + swz(n,g)*8];
    }
    #pragma unroll
    for (int mt = 0; mt < 2; ++mt)
      #pragma unroll
      for (int nt = 0; nt < 4; ++nt)
        acc[mt][nt] = __builtin_amdgcn_mfma_f32_16x16x32_bf16(af[mt], bfr[nt], acc[mt][nt], 0, 0, 0);
  }
  // ---- epilogue ----
  #pragma unroll
  for (int mt = 0; mt < 2; ++mt) {
    #pragma unroll
    for (int nt = 0; nt < 4; ++nt) {
      int col = wn*64 + nt*16 + lr;
      #pragma unroll
      for (int q = 0; q < 4; ++q) {
        int rl = wm*32 + mt*16 + g*4 + q;
        long row = m0 + rl;
        float v = acc[mt][nt][q];
        if (EPI == 0) {
          Cf[(long)b*sC + row*HID_ + col] = v;
        } else if (EPI == 1) {
          v /= dsum[rl];
          v = (v > 0.f) ? v : expm1f(v);
          Cb[(long)b*sC + row*HID_ + col] = f2b(v);
        } else if (EPI == 2) {
          v /= dsum[rl];
          Cf[(long)b*sC + row*HID_ + col] = v;
        } else {
          Cb[(long)b*sC + row*HID_ + col] = f2b(v);
        }
      }
    }
  }
  if (EPI == 0 && t < 64) den1o[(long)b*NE_ + m0 + t] = dsum[t];
}

// edge = num/den1 -> ET[b][h][e] (bf16, transposed); f2[r] = edge_row . cf2
__global__ void k_edge_fin(const float* __restrict__ num, const float* __restrict__ den1,
                           const float* __restrict__ consts, int layer,
                           unsigned short* __restrict__ ET, float* __restrict__ f2)
{
  __shared__ __attribute__((aligned(16))) unsigned short T[64][132];
  int b = blockIdx.y, e0 = blockIdx.x * 64, t = threadIdx.x;  // 256
  int r = t >> 2, h0 = (t & 3) * 32;
  const float* cf2 = consts + layer*384 + 256;
  long erow = (long)b*NE_ + e0 + r;
  float d = 1.f / den1[erow];
  const float* np = num + erow*HID_ + h0;
  float p = 0.f;
  #pragma unroll
  for (int j = 0; j < 32; j += 4) {
    f32x4 xv = *(const f32x4*)(np + j);
    u16x4 o;
    #pragma unroll
    for (int k2 = 0; k2 < 4; ++k2) {
      float v = xv[k2] * d;
      o[k2] = f2b(v);
      p += v * cf2[h0 + j + k2];
    }
    *(u16x4*)&T[r][h0+j] = o;
  }
  p += __shfl_down(p, 2, 4); p += __shfl_down(p, 1, 4);
  if ((t & 3) == 0) f2[erow] = p;
  __syncthreads();
  int h = t >> 1, eh = (t & 1) * 32;
  unsigned short* dst = ET + ((long)b*HID_ + h)*NE_ + e0 + eh;
  #pragma unroll
  for (int j = 0; j < 32; j += 8) {
    u16x8 o;
    #pragma unroll
    for (int k2 = 0; k2 < 8; ++k2) o[k2] = T[eh+j+k2][h];
    *(u16x8*)&dst[j] = o;
  }
}

__global__ void k_maxf2(const float* __restrict__ f2, const float* __restrict__ Mf1,
                        float* __restrict__ C2)
{
  int b = blockIdx.x, t = threadIdx.x;  // 256
  __shared__ float s1[256];
  s1[t] = f2[b*NE_ + t]; __syncthreads();
  for (int s = 128; s > 0; s >>= 1) { if (t < s) s1[t] = fmaxf(s1[t], s1[t+s]); __syncthreads(); }
  if (t == 0) { float z = Mf1[b] + s1[0]; C2[b] = (z >= 0.f) ? z : ALPHA_ * z; }
}

__global__ void k_pool(const int* __restrict__ alias, const float* __restrict__ masks,
                       const float* __restrict__ X3, const float* __restrict__ ln_g,
                       const float* __restrict__ ln_b, float* __restrict__ out)
{
  __shared__ float accs[256];
  __shared__ float ms[2];
  __shared__ float red[128];
  int b = blockIdx.x, t = threadIdx.x;   // 256
  int h = t & 127, half = t >> 7;
  float acc = 0.f, msum = 0.f;
  for (int l = half*256; l < half*256 + 256; ++l) {
    float mv = masks[b*L_ + l];
    int idx  = alias[b*L_ + l];
    acc  += mv * mv * X3[((long)b*NN_ + idx)*HID_ + h];
    msum += mv;
  }
  accs[t] = acc;
  if (h == 0) ms[half] = msum;
  __syncthreads();
  float bv = 0.f;
  if (t < 128) bv = (accs[t] + accs[t+128]) / (ms[0] + ms[1]);
  __syncthreads();
  if (t < 128) red[t] = bv;
  __syncthreads();
  for (int s = 64; s > 0; s >>= 1) { if (t < s) red[t] += red[t+s]; __syncthreads(); }
  float mu = red[0] * (1.f / HID_);
  __syncthreads();
  float dv = bv - mu;
  if (t < 128) red[t] = dv * dv;
  __syncthreads();
  for (int s = 64; s > 0; s >>= 1) { if (t < s) red[t] += red[t+s]; __syncthreads(); }
  float var = red[0] * (1.f / HID_);
  if (t < 128) out[b*HID_ + t] = dv / sqrtf(var + 1e-6f) * ln_g[t] + ln_b[t];
}

extern "C" void kernel_launch(void* const* d_in, const int* in_sizes, int n_in,
                              void* d_out, int out_size, void* d_ws, size_t ws_size,
                              hipStream_t stream)
{
  const int*   items = (const int*)d_in[0];
  const int*   alias = (const int*)d_in[1];
  const float* masks = (const float*)d_in[2];
  const float* adj   = (const float*)d_in[3];
  const float* emb   = (const float*)d_in[4];
  const float* w2_1  = (const float*)d_in[5];
  const float* w3_1  = (const float*)d_in[6];
  const float* a_1   = (const float*)d_in[7];
  const float* a2_1  = (const float*)d_in[8];
  const float* wc_1  = (const float*)d_in[9];
  const float* w_2   = (const float*)d_in[10];
  const float* w2_2  = (const float*)d_in[11];
  const float* w3_2  = (const float*)d_in[12];
  const float* a_2   = (const float*)d_in[13];
  const float* a2_2  = (const float*)d_in[14];
  const float* wc_2  = (const float*)d_in[15];
  const float* ln_g  = (const float*)d_in[16];
  const float* ln_b  = (const float*)d_in[17];
  float* out = (float*)d_out;

  char* ws = (char*)d_ws;
  size_t off = 0;
  auto alloc = [&](size_t bytes) -> void* {
    void* p = ws + off; off += (bytes + 255) / 256 * 256; return p;
  };
  unsigned short* ADJT = (unsigned short*)alloc((size_t)B_*NN_*NE_*2);
  unsigned short* YT   = (unsigned short*)alloc((size_t)B_*HID_*NN_*2);
  unsigned short* ET   = (unsigned short*)alloc((size_t)B_*HID_*NE_*2);
  unsigned short* X2BF = (unsigned short*)alloc((size_t)B_*NN_*HID_*2);
  unsigned short* XWBF = (unsigned short*)alloc((size_t)B_*NN_*HID_*2);
  float* ENUM  = (float*)alloc((size_t)B_*NE_*HID_*4);
  float* X3    = (float*)alloc((size_t)B_*NN_*HID_*4);
  float* e1    = (float*)alloc((size_t)B_*NN_*4);
  float* f1    = (float*)alloc((size_t)B_*NN_*4);
  float* w1    = (float*)alloc((size_t)B_*NN_*4);
  float* den1  = (float*)alloc((size_t)B_*NE_*4);
  float* f2    = (float*)alloc((size_t)B_*NE_*4);
  float* M1    = (float*)alloc(B_*4);
  float* Mf1   = (float*)alloc(B_*4);
  float* C2    = (float*)alloc(B_*4);
  float* consts= (float*)alloc(772*4);
  unsigned short* W2T = (unsigned short*)alloc((size_t)HID_*HID_*2);
  if (off > ws_size) return;

  const long sAdj = (long)NE_*NN_, sAdjT = (long)NN_*NE_;
  const long sYT = (long)HID_*NN_, sET = (long)HID_*NE_;
  const long sCE = (long)NE_*HID_, sCN = (long)NN_*HID_;

  k_consts<<<9, 128, 0, stream>>>(w2_1, w3_1, a_1, a2_1, wc_1, w2_2, w3_2, a_2, a2_2, wc_2,
                                  w_2, consts, W2T);
  k_adjT<<<dim3(NN_/64, NE_/64, B_), 256, 0, stream>>>(adj, ADJT);

  // ---------------- layer 1 ----------------
  k_proj<<<B_*NN_/4, 256, 0, stream>>>(emb, nullptr, items, consts, 0, e1, f1);
  k_bmax<<<B_, 256, 0, stream>>>(e1, f1, M1, Mf1);
  k_w1y<0><<<dim3(NN_/64, B_), 256, 0, stream>>>(e1, M1, emb, nullptr, items, w1, YT);
  k_mgemm<0,0><<<dim3(NE_/64, B_), 256, 0, stream>>>(adj, sAdj, NN_, YT, sYT, NN_,
        ENUM, nullptr, sCE, w1, den1, nullptr, nullptr, nullptr);
  k_edge_fin<<<dim3(NE_/64, B_), 256, 0, stream>>>(ENUM, den1, consts, 0, ET, f2);
  k_maxf2<<<B_, 256, 0, stream>>>(f2, Mf1, C2);
  k_mgemm<1,1><<<dim3(NN_/64, B_), 256, 0, stream>>>(ADJT, sAdjT, NE_, ET, sET, NE_,
        nullptr, X2BF, sCN, nullptr, nullptr, f1, f2, C2);

  // ---------------- layer 2 ----------------
  k_proj<<<B_*NN_/4, 256, 0, stream>>>(nullptr, X2BF, nullptr, consts, 1, e1, f1);
  k_bmax<<<B_, 256, 0, stream>>>(e1, f1, M1, Mf1);
  k_mgemm<2,3><<<dim3(B_*NN_/64, 1), 256, 0, stream>>>(X2BF, 0, HID_, W2T, 0, HID_,
        nullptr, XWBF, 0, nullptr, nullptr, nullptr, nullptr, nullptr);
  k_w1y<1><<<dim3(NN_/64, B_), 256, 0, stream>>>(e1, M1, nullptr, XWBF, nullptr, w1, YT);
  k_mgemm<0,0><<<dim3(NE_/64, B_), 256, 0, stream>>>(adj, sAdj, NN_, YT, sYT, NN_,
        ENUM, nullptr, sCE, w1, den1, nullptr, nullptr, nullptr);
  k_edge_fin<<<dim3(NE_/64, B_), 256, 0, stream>>>(ENUM, den1, consts, 1, ET, f2);
  k_maxf2<<<B_, 256, 0, stream>>>(f2, Mf1, C2);
  k_mgemm<1,2><<<dim3(NN_/64, B_), 256, 0, stream>>>(ADJT, sAdjT, NE_, ET, sET, NE_,
        X3, nullptr, sCN, nullptr, nullptr, f1, f2, C2);

  // ---------------- pool + layernorm ----------------
  k_pool<<<B_, 256, 0, stream>>>(alias, masks, X3, ln_g, ln_b, out);
}

// Round 4
// 187.340 us; speedup vs baseline: 3.4543x; 1.2405x over previous
//
#include <hip/hip_runtime.h>
#include <hip/hip_bf16.h>

typedef __hip_bfloat16 bf16;
typedef __attribute__((ext_vector_type(8))) unsigned short u16x8;
typedef __attribute__((ext_vector_type(4))) unsigned short u16x4;
typedef __attribute__((ext_vector_type(4))) float f32x4;
typedef __attribute__((ext_vector_type(8))) short bf16x8;

#define B_   64
#define NE_  256
#define NN_  1024
#define L_   512
#define HID_ 128
#define ALPHA_ 0.2f

__device__ __forceinline__ float bfu(unsigned short u){
  unsigned int x = ((unsigned int)u) << 16;
  union { unsigned int i; float f; } c; c.i = x; return c.f;
}
__device__ __forceinline__ unsigned short f2b(float f){
  bf16 h = __float2bfloat16(f);
  union { bf16 b; unsigned short u; } c; c.b = h; return c.u;
}
// chunk swizzle: involution in c for fixed r; spreads frag reads to <=2-way
__device__ __forceinline__ int swz(int r, int c){ return (c ^ (r & 3) ^ ((r >> 2) & 3)) & 3; }

// consts layout (floats): [0:128) ce1_1, [128:256) cf1_1, [256:384) cf2_1,
// [384:512) ce1_2, [512:640) cf1_2, [640:768) cf2_2, [768] s0_1, [769] s0_2
__global__ void k_consts(const float* w2_1, const float* w3_1,
                         const float* a_1, const float* a2_1, const float* wc_1,
                         const float* w2_2, const float* w3_2,
                         const float* a_2, const float* a2_2, const float* wc_2,
                         const float* w_2,
                         float* consts, unsigned short* W2T)
{
  int blk = blockIdx.x, t = threadIdx.x; // 128 threads
  __shared__ float red[128];
  if (blk < 6) {
    const float* M; const float* v;
    switch (blk) {
      case 0: M = w2_1; v = a_1  + 128; break;
      case 1: M = w2_1; v = a2_1;       break;
      case 2: M = w3_1; v = a2_1 + 128; break;
      case 3: M = w2_2; v = a_2  + 128; break;
      case 4: M = w2_2; v = a2_2;       break;
      default: M = w3_2; v = a2_2 + 128; break;
    }
    float acc = 0.f;
    for (int o = 0; o < 128; ++o) acc += M[t*128 + o] * v[o];
    consts[blk*128 + t] = acc;
  } else if (blk < 8) {
    const float* wc = (blk == 6) ? wc_1 : wc_2;
    const float* a  = (blk == 6) ? a_1  : a_2;
    red[t] = wc[t] * a[t];
    __syncthreads();
    for (int s = 64; s > 0; s >>= 1) { if (t < s) red[t] += red[t + s]; __syncthreads(); }
    if (t == 0) consts[768 + (blk - 6)] = red[0];
  } else {
    // W2T[h][k] = w_2[k][h]
    for (int k = 0; k < 128; ++k) W2T[t*128 + k] = f2b(w_2[k*128 + t]);
  }
}

// ADJB[b][e][n] = bf16(adj); ADJT[b][n][e] = bf16(adj[b][e][n])
__global__ void k_prep(const float* __restrict__ adj,
                       unsigned short* __restrict__ ADJB, unsigned short* __restrict__ ADJT)
{
  __shared__ unsigned short tile[64][65];
  int b  = blockIdx.z;
  int e0 = blockIdx.y * 64;
  int n0 = blockIdx.x * 64;
  int t  = threadIdx.x;                 // 256
  int lr = t >> 2, lc0 = (t & 3) * 16;
  const float* src = adj + ((long)b*NE_ + e0 + lr)*NN_ + n0 + lc0;
  u16x8 s0v, s1v;
  #pragma unroll
  for (int j = 0; j < 8; j += 4) {
    f32x4 v = *(const f32x4*)(src + j);
    #pragma unroll
    for (int k = 0; k < 4; ++k) { s0v[j+k] = f2b(v[k]); tile[lr][lc0+j+k] = s0v[j+k]; }
  }
  #pragma unroll
  for (int j = 0; j < 8; j += 4) {
    f32x4 v = *(const f32x4*)(src + 8 + j);
    #pragma unroll
    for (int k = 0; k < 4; ++k) { s1v[j+k] = f2b(v[k]); tile[lr][lc0+8+j+k] = s1v[j+k]; }
  }
  unsigned short* db = ADJB + ((long)b*NE_ + e0 + lr)*NN_ + n0 + lc0;
  *(u16x8*)db = s0v;
  *(u16x8*)(db + 8) = s1v;
  __syncthreads();
  u16x8 o0, o1;
  #pragma unroll
  for (int j = 0; j < 8; ++j) o0[j] = tile[lc0 + j][lr];
  #pragma unroll
  for (int j = 0; j < 8; ++j) o1[j] = tile[lc0 + 8 + j][lr];
  unsigned short* dst = ADJT + ((long)b*NN_ + n0 + lr)*NE_ + e0 + lc0;
  *(u16x8*)dst = o0;
  *(u16x8*)(dst + 8) = o1;
}

// fused: e1/f1 row-dots + w1=exp(e1) + YT[b][h][n] = bf16(w1*x) transposed write
template<int SRCBF>
__global__ void k_fproj(const float* __restrict__ srcF, const unsigned short* __restrict__ srcB,
                        const int* __restrict__ gitems,
                        const float* __restrict__ consts, int layer,
                        float* __restrict__ w1, float* __restrict__ f1,
                        unsigned short* __restrict__ YT)
{
  __shared__ float ce1s[128], cf1s[128];
  __shared__ __attribute__((aligned(16))) unsigned short T[64][132];
  int b = blockIdx.y, n0 = blockIdx.x * 64, t = threadIdx.x;  // 256
  if (t < 128) { ce1s[t] = consts[layer*384 + t]; cf1s[t] = consts[layer*384 + 128 + t]; }
  __syncthreads();
  int r = t >> 2, h0 = (t & 3) * 32;
  long row = (long)b*NN_ + n0 + r;
  float s0 = consts[768 + layer];
  float xv[32];
  if (SRCBF) {
    const unsigned short* sp = srcB + row*HID_ + h0;
    #pragma unroll
    for (int j = 0; j < 32; j += 8) {
      u16x8 v = *(const u16x8*)(sp + j);
      #pragma unroll
      for (int k = 0; k < 8; ++k) xv[j+k] = bfu(v[k]);
    }
  } else {
    const float* sp = srcF + (long)gitems[row]*HID_ + h0;
    #pragma unroll
    for (int j = 0; j < 32; j += 4) {
      f32x4 v = *(const f32x4*)(sp + j);
      #pragma unroll
      for (int k = 0; k < 4; ++k) xv[j+k] = v[k];
    }
  }
  float p1 = 0.f, p2 = 0.f;
  #pragma unroll
  for (int j = 0; j < 32; ++j) { p1 += xv[j]*ce1s[h0+j]; p2 += xv[j]*cf1s[h0+j]; }
  p1 += __shfl_xor(p1, 1, 4); p1 += __shfl_xor(p1, 2, 4);
  p2 += __shfl_xor(p2, 1, 4); p2 += __shfl_xor(p2, 2, 4);
  float z = p1 + s0; z = (z >= 0.f) ? z : ALPHA_*z;
  float w = __expf(z);
  if ((t & 3) == 0) { w1[row] = w; f1[row] = p2; }
  #pragma unroll
  for (int j = 0; j < 32; j += 4) {
    u16x4 o;
    #pragma unroll
    for (int k = 0; k < 4; ++k) o[k] = f2b(w * xv[j+k]);
    *(u16x4*)&T[r][h0+j] = o;
  }
  __syncthreads();
  int h = t >> 1, nh = (t & 1) * 32;
  unsigned short* dst = YT + ((long)b*HID_ + h)*NN_ + n0 + nh;
  #pragma unroll
  for (int j = 0; j < 32; j += 8) {
    u16x8 o;
    #pragma unroll
    for (int k = 0; k < 8; ++k) o[k] = T[nh+j+k][h];
    *(u16x8*)&dst[j] = o;
  }
}

// GEMM1: U = ADJB@Y (K=NN), den1 in-LDS; epilogue: edge=U/den (opt @W_2), f2, ET transposed
template<int TRANSFER>
__global__ __launch_bounds__(256) void k_gemm_edge(
    const unsigned short* __restrict__ ADJB,
    const unsigned short* __restrict__ YT,
    const float* __restrict__ w1v,
    const float* __restrict__ consts, int layer,
    const unsigned short* __restrict__ W2T,
    unsigned short* __restrict__ ET,
    float* __restrict__ f2o)
{
  __shared__ __attribute__((aligned(16))) unsigned short SM[8704]; // As|Bs then U[64][136]
  __shared__ float dsum[64];
  unsigned short* As = SM;            // [64][32]
  unsigned short* Bs = SM + 2048;     // [128][32]
  const int b = blockIdx.y;
  const long e0 = (long)blockIdx.x * 64;
  const int t = threadIdx.x;
  const int lane = t & 63;
  const int w = t >> 6, wm = w >> 1, wn = w & 1;
  const int r4 = t >> 2, c4 = t & 3;
  const int lr = lane & 15, g = lane >> 4;

  f32x4 acc[2][4];
  #pragma unroll
  for (int i = 0; i < 2; ++i)
    #pragma unroll
    for (int j = 0; j < 4; ++j) acc[i][j] = (f32x4){0.f,0.f,0.f,0.f};
  if ((t & 3) == 0) dsum[r4] = 0.f;

  const unsigned short* Ab = ADJB + (long)b*NE_*NN_ + (e0 + r4)*NN_;
  const unsigned short* Bb = YT + (long)b*HID_*NN_;
  const float* wb = w1v + (long)b*NN_;

  for (int kc = 0; kc < NN_; kc += 32) {
    if (kc) __syncthreads();
    // stage A + den1 dot
    {
      u16x8 av = *(const u16x8*)(Ab + kc + c4*8);
      const float* wp = wb + kc + c4*8;
      f32x4 w0 = *(const f32x4*)wp;
      f32x4 w1x = *(const f32x4*)(wp + 4);
      float dot = bfu(av[0])*w0[0]+bfu(av[1])*w0[1]+bfu(av[2])*w0[2]+bfu(av[3])*w0[3]
                + bfu(av[4])*w1x[0]+bfu(av[5])*w1x[1]+bfu(av[6])*w1x[2]+bfu(av[7])*w1x[3];
      *(u16x8*)&As[r4*32 + swz(r4,c4)*8] = av;
      dot += __shfl_down(dot, 2, 4); dot += __shfl_down(dot, 1, 4);
      if ((lane & 3) == 0) dsum[r4] += dot;
    }
    // stage B
    #pragma unroll
    for (int jj = 0; jj < 2; ++jj) {
      int rB = jj*64 + r4;
      u16x8 bv = *(const u16x8*)(Bb + (long)rB*NN_ + kc + c4*8);
      *(u16x8*)&Bs[rB*32 + swz(rB,c4)*8] = bv;
    }
    __syncthreads();
    bf16x8 af[2], bfr[4];
    #pragma unroll
    for (int mt = 0; mt < 2; ++mt) {
      int r = wm*32 + mt*16 + lr;
      af[mt] = *(const bf16x8*)&As[r*32 + swz(r,g)*8];
    }
    #pragma unroll
    for (int nt = 0; nt < 4; ++nt) {
      int n = wn*64 + nt*16 + lr;
      bfr[nt] = *(const bf16x8*)&Bs[n*32 + swz(n,g)*8];
    }
    #pragma unroll
    for (int mt = 0; mt < 2; ++mt)
      #pragma unroll
      for (int nt = 0; nt < 4; ++nt)
        acc[mt][nt] = __builtin_amdgcn_mfma_f32_16x16x32_bf16(af[mt], bfr[nt], acc[mt][nt], 0, 0, 0);
  }
  __syncthreads();   // As/Bs dead; reuse as U
  // U[rl][col] = bf16(acc / den1)
  #pragma unroll
  for (int mt = 0; mt < 2; ++mt)
    #pragma unroll
    for (int nt = 0; nt < 4; ++nt) {
      int col = wn*64 + nt*16 + lr;
      #pragma unroll
      for (int q = 0; q < 4; ++q) {
        int rl = wm*32 + mt*16 + g*4 + q;
        SM[rl*136 + col] = f2b(acc[mt][nt][q] / dsum[rl]);
      }
    }
  __syncthreads();
  if (TRANSFER) {
    // edge = U @ W_2  (mini-MFMA, B from global W2T[h][k])
    f32x4 acc2[2][4];
    #pragma unroll
    for (int i = 0; i < 2; ++i)
      #pragma unroll
      for (int j = 0; j < 4; ++j) acc2[i][j] = (f32x4){0.f,0.f,0.f,0.f};
    #pragma unroll
    for (int kc2 = 0; kc2 < 4; ++kc2) {
      bf16x8 af[2], bfr[4];
      #pragma unroll
      for (int mt = 0; mt < 2; ++mt) {
        int r = wm*32 + mt*16 + lr;
        af[mt] = *(const bf16x8*)&SM[r*136 + kc2*32 + g*8];
      }
      #pragma unroll
      for (int nt = 0; nt < 4; ++nt) {
        int n = wn*64 + nt*16 + lr;
        bfr[nt] = *(const bf16x8*)(W2T + n*128 + kc2*32 + g*8);
      }
      #pragma unroll
      for (int mt = 0; mt < 2; ++mt)
        #pragma unroll
        for (int nt = 0; nt < 4; ++nt)
          acc2[mt][nt] = __builtin_amdgcn_mfma_f32_16x16x32_bf16(af[mt], bfr[nt], acc2[mt][nt], 0, 0, 0);
    }
    __syncthreads();
    #pragma unroll
    for (int mt = 0; mt < 2; ++mt)
      #pragma unroll
      for (int nt = 0; nt < 4; ++nt) {
        int col = wn*64 + nt*16 + lr;
        #pragma unroll
        for (int q = 0; q < 4; ++q) {
          int rl = wm*32 + mt*16 + g*4 + q;
          SM[rl*136 + col] = f2b(acc2[mt][nt][q]);
        }
      }
    __syncthreads();
  }
  // f2 = edge . cf2
  {
    const float* cf2 = consts + layer*384 + 256;
    int r = t >> 2, h0 = (t & 3) * 32;
    float p = 0.f;
    #pragma unroll
    for (int j = 0; j < 32; ++j) p += bfu(SM[r*136 + h0 + j]) * cf2[h0 + j];
    p += __shfl_down(p, 2, 4); p += __shfl_down(p, 1, 4);
    if ((t & 3) == 0) f2o[(long)b*NE_ + e0 + r] = p;
  }
  // ET[b][h][e] transposed write
  {
    int h = t >> 1, eh = (t & 1) * 32;
    unsigned short* dst = ET + ((long)b*HID_ + h)*NE_ + e0 + eh;
    #pragma unroll
    for (int j = 0; j < 32; j += 8) {
      u16x8 o;
      #pragma unroll
      for (int k = 0; k < 8; ++k) o[k] = SM[(eh+j+k)*136 + h];
      *(u16x8*)&dst[j] = o;
    }
  }
}

// GEMM2: A[n][e] = adjT*exp(leaky(f1[n]+f2[e])) on the fly; C = (A@edge)/rowsum
// EPI 1: elu -> bf16 Cb ; EPI 2: f32 Cf
template<int EPI>
__global__ __launch_bounds__(256) void k_gemm_att(
    const unsigned short* __restrict__ ADJT,
    const unsigned short* __restrict__ ET,
    const float* __restrict__ f1v, const float* __restrict__ f2v,
    float* __restrict__ Cf, unsigned short* __restrict__ Cb)
{
  __shared__ __attribute__((aligned(16))) unsigned short As[64*32];
  __shared__ __attribute__((aligned(16))) unsigned short Bs[128*32];
  __shared__ float dsum[64];
  const int b = blockIdx.y;
  const long m0 = (long)blockIdx.x * 64;
  const int t = threadIdx.x;
  const int lane = t & 63;
  const int w = t >> 6, wm = w >> 1, wn = w & 1;
  const int r4 = t >> 2, c4 = t & 3;
  const int lr = lane & 15, g = lane >> 4;

  f32x4 acc[2][4];
  #pragma unroll
  for (int i = 0; i < 2; ++i)
    #pragma unroll
    for (int j = 0; j < 4; ++j) acc[i][j] = (f32x4){0.f,0.f,0.f,0.f};
  if ((t & 3) == 0) dsum[r4] = 0.f;

  const float f1r = f1v[(long)b*NN_ + m0 + r4];
  const unsigned short* Ab = ADJT + (long)b*NN_*NE_ + (m0 + r4)*NE_;
  const unsigned short* Bb = ET + (long)b*HID_*NE_;
  const float* f2b_ = f2v + (long)b*NE_;

  for (int kc = 0; kc < NE_; kc += 32) {
    if (kc) __syncthreads();
    {
      u16x8 mv = *(const u16x8*)(Ab + kc + c4*8);
      const float* f2p = f2b_ + kc + c4*8;
      f32x4 f20 = *(const f32x4*)f2p;
      f32x4 f21 = *(const f32x4*)(f2p + 4);
      float fv[8] = {f20[0],f20[1],f20[2],f20[3],f21[0],f21[1],f21[2],f21[3]};
      u16x8 av; float dot = 0.f;
      #pragma unroll
      for (int j = 0; j < 8; ++j) {
        float z = f1r + fv[j];
        z = (z >= 0.f) ? z : ALPHA_ * z;
        float wt = (bfu(mv[j]) > 0.f) ? __expf(z) : 0.f;
        unsigned short ub = f2b(wt);
        av[j] = ub; dot += bfu(ub);
      }
      *(u16x8*)&As[r4*32 + swz(r4,c4)*8] = av;
      dot += __shfl_down(dot, 2, 4); dot += __shfl_down(dot, 1, 4);
      if ((lane & 3) == 0) dsum[r4] += dot;
    }
    #pragma unroll
    for (int jj = 0; jj < 2; ++jj) {
      int rB = jj*64 + r4;
      u16x8 bv = *(const u16x8*)(Bb + (long)rB*NE_ + kc + c4*8);
      *(u16x8*)&Bs[rB*32 + swz(rB,c4)*8] = bv;
    }
    __syncthreads();
    bf16x8 af[2], bfr[4];
    #pragma unroll
    for (int mt = 0; mt < 2; ++mt) {
      int r = wm*32 + mt*16 + lr;
      af[mt] = *(const bf16x8*)&As[r*32 + swz(r,g)*8];
    }
    #pragma unroll
    for (int nt = 0; nt < 4; ++nt) {
      int n = wn*64 + nt*16 + lr;
      bfr[nt] = *(const bf16x8*)&Bs[n*32 + swz(n,g)*8];
    }
    #pragma unroll
    for (int mt = 0; mt < 2; ++mt)
      #pragma unroll
      for (int nt = 0; nt < 4; ++nt)
        acc[mt][nt] = __builtin_amdgcn_mfma_f32_16x16x32_bf16(af[mt], bfr[nt], acc[mt][nt], 0, 0, 0);
  }
  #pragma unroll
  for (int mt = 0; mt < 2; ++mt)
    #pragma unroll
    for (int nt = 0; nt < 4; ++nt) {
      int col = wn*64 + nt*16 + lr;
      #pragma unroll
      for (int q = 0; q < 4; ++q) {
        int rl = wm*32 + mt*16 + g*4 + q;
        long row = m0 + rl;
        float v = acc[mt][nt][q] / dsum[rl];
        if (EPI == 1) {
          v = (v > 0.f) ? v : expm1f(v);
          Cb[(long)b*NN_*HID_ + row*HID_ + col] = f2b(v);
        } else {
          Cf[(long)b*NN_*HID_ + row*HID_ + col] = v;
        }
      }
    }
}

__global__ void k_pool(const int* __restrict__ alias, const float* __restrict__ masks,
                       const float* __restrict__ X3, const float* __restrict__ ln_g,
                       const float* __restrict__ ln_b, float* __restrict__ out)
{
  __shared__ float accs[256];
  __shared__ float ms[2];
  __shared__ float red[128];
  int b = blockIdx.x, t = threadIdx.x;   // 256
  int h = t & 127, half = t >> 7;
  float acc = 0.f, msum = 0.f;
  for (int l = half*256; l < half*256 + 256; ++l) {
    float mv = masks[b*L_ + l];
    int idx  = alias[b*L_ + l];
    acc  += mv * mv * X3[((long)b*NN_ + idx)*HID_ + h];
    msum += mv;
  }
  accs[t] = acc;
  if (h == 0) ms[half] = msum;
  __syncthreads();
  float bv = 0.f;
  if (t < 128) bv = (accs[t] + accs[t+128]) / (ms[0] + ms[1]);
  __syncthreads();
  if (t < 128) red[t] = bv;
  __syncthreads();
  for (int s = 64; s > 0; s >>= 1) { if (t < s) red[t] += red[t+s]; __syncthreads(); }
  float mu = red[0] * (1.f / HID_);
  __syncthreads();
  float dv = bv - mu;
  if (t < 128) red[t] = dv * dv;
  __syncthreads();
  for (int s = 64; s > 0; s >>= 1) { if (t < s) red[t] += red[t+s]; __syncthreads(); }
  float var = red[0] * (1.f / HID_);
  if (t < 128) out[b*HID_ + t] = dv / sqrtf(var + 1e-6f) * ln_g[t] + ln_b[t];
}

extern "C" void kernel_launch(void* const* d_in, const int* in_sizes, int n_in,
                              void* d_out, int out_size, void* d_ws, size_t ws_size,
                              hipStream_t stream)
{
  const int*   items = (const int*)d_in[0];
  const int*   alias = (const int*)d_in[1];
  const float* masks = (const float*)d_in[2];
  const float* adj   = (const float*)d_in[3];
  const float* emb   = (const float*)d_in[4];
  const float* w2_1  = (const float*)d_in[5];
  const float* w3_1  = (const float*)d_in[6];
  const float* a_1   = (const float*)d_in[7];
  const float* a2_1  = (const float*)d_in[8];
  const float* wc_1  = (const float*)d_in[9];
  const float* w_2   = (const float*)d_in[10];
  const float* w2_2  = (const float*)d_in[11];
  const float* w3_2  = (const float*)d_in[12];
  const float* a_2   = (const float*)d_in[13];
  const float* a2_2  = (const float*)d_in[14];
  const float* wc_2  = (const float*)d_in[15];
  const float* ln_g  = (const float*)d_in[16];
  const float* ln_b  = (const float*)d_in[17];
  float* out = (float*)d_out;

  char* ws = (char*)d_ws;
  size_t off = 0;
  auto alloc = [&](size_t bytes) -> void* {
    void* p = ws + off; off += (bytes + 255) / 256 * 256; return p;
  };
  unsigned short* ADJB = (unsigned short*)alloc((size_t)B_*NE_*NN_*2);
  unsigned short* ADJT = (unsigned short*)alloc((size_t)B_*NN_*NE_*2);
  unsigned short* YT   = (unsigned short*)alloc((size_t)B_*HID_*NN_*2);
  unsigned short* ET   = (unsigned short*)alloc((size_t)B_*HID_*NE_*2);
  unsigned short* X2BF = (unsigned short*)alloc((size_t)B_*NN_*HID_*2);
  float* X3    = (float*)alloc((size_t)B_*NN_*HID_*4);
  float* w1    = (float*)alloc((size_t)B_*NN_*4);
  float* f1    = (float*)alloc((size_t)B_*NN_*4);
  float* f2    = (float*)alloc((size_t)B_*NE_*4);
  float* consts= (float*)alloc(772*4);
  unsigned short* W2T = (unsigned short*)alloc((size_t)HID_*HID_*2);
  if (off > ws_size) return;

  k_consts<<<9, 128, 0, stream>>>(w2_1, w3_1, a_1, a2_1, wc_1, w2_2, w3_2, a_2, a2_2, wc_2,
                                  w_2, consts, W2T);
  k_prep<<<dim3(NN_/64, NE_/64, B_), 256, 0, stream>>>(adj, ADJB, ADJT);

  // ---------------- layer 1 ----------------
  k_fproj<0><<<dim3(NN_/64, B_), 256, 0, stream>>>(emb, nullptr, items, consts, 0, w1, f1, YT);
  k_gemm_edge<0><<<dim3(NE_/64, B_), 256, 0, stream>>>(ADJB, YT, w1, consts, 0, W2T, ET, f2);
  k_gemm_att<1><<<dim3(NN_/64, B_), 256, 0, stream>>>(ADJT, ET, f1, f2, nullptr, X2BF);

  // ---------------- layer 2 ----------------
  k_fproj<1><<<dim3(NN_/64, B_), 256, 0, stream>>>(nullptr, X2BF, nullptr, consts, 1, w1, f1, YT);
  k_gemm_edge<1><<<dim3(NE_/64, B_), 256, 0, stream>>>(ADJB, YT, w1, consts, 1, W2T, ET, f2);
  k_gemm_att<2><<<dim3(NN_/64, B_), 256, 0, stream>>>(ADJT, ET, f1, f2, X3, nullptr);

  // ---------------- pool + layernorm ----------------
  k_pool<<<B_, 256, 0, stream>>>(alias, masks, X3, ln_g, ln_b, out);
}

// Round 6
// 140.324 us; speedup vs baseline: 4.6116x; 1.3351x over previous
//
#include <hip/hip_runtime.h>
#include <hip/hip_bf16.h>

typedef __hip_bfloat16 bf16;
typedef __attribute__((ext_vector_type(8))) unsigned short u16x8;
typedef __attribute__((ext_vector_type(4))) unsigned short u16x4;
typedef __attribute__((ext_vector_type(4))) float f32x4;
typedef __attribute__((ext_vector_type(8))) short bf16x8;
typedef __attribute__((ext_vector_type(16))) unsigned char u8x16;

#define B_   64
#define NE_  256
#define NN_  1024
#define L_   512
#define HID_ 128
#define ALPHA_ 0.2f

__device__ __forceinline__ float bfu(unsigned short u){
  unsigned int x = ((unsigned int)u) << 16;
  union { unsigned int i; float f; } c; c.i = x; return c.f;
}
__device__ __forceinline__ unsigned short f2b(float f){
  bf16 h = __float2bfloat16(f);
  union { bf16 b; unsigned short u; } c; c.b = h; return c.u;
}
// chunk swizzle: involution in c for fixed r; spreads frag reads to <=2-way
__device__ __forceinline__ int swz(int r, int c){ return (c ^ (r & 3) ^ ((r >> 2) & 3)) & 3; }

// consts layout (floats): [0:128) ce1_1, [128:256) cf1_1, [256:384) cf2_1,
// [384:512) ce1_2, [512:640) cf1_2, [640:768) cf2_2, [768] s0_1, [769] s0_2
__global__ void k_consts(const float* w2_1, const float* w3_1,
                         const float* a_1, const float* a2_1, const float* wc_1,
                         const float* w2_2, const float* w3_2,
                         const float* a_2, const float* a2_2, const float* wc_2,
                         const float* w_2,
                         float* consts, unsigned short* W2T)
{
  int blk = blockIdx.x, t = threadIdx.x; // 128 threads
  __shared__ float red[128];
  if (blk < 6) {
    const float* M; const float* v;
    switch (blk) {
      case 0: M = w2_1; v = a_1  + 128; break;
      case 1: M = w2_1; v = a2_1;       break;
      case 2: M = w3_1; v = a2_1 + 128; break;
      case 3: M = w2_2; v = a_2  + 128; break;
      case 4: M = w2_2; v = a2_2;       break;
      default: M = w3_2; v = a2_2 + 128; break;
    }
    float acc = 0.f;
    for (int o = 0; o < 128; ++o) acc += M[t*128 + o] * v[o];
    consts[blk*128 + t] = acc;
  } else if (blk < 8) {
    const float* wc = (blk == 6) ? wc_1 : wc_2;
    const float* a  = (blk == 6) ? a_1  : a_2;
    red[t] = wc[t] * a[t];
    __syncthreads();
    for (int s = 64; s > 0; s >>= 1) { if (t < s) red[t] += red[t + s]; __syncthreads(); }
    if (t == 0) consts[768 + (blk - 6)] = red[0];
  } else {
    // W2T[h][k] = w_2[k][h]
    for (int k = 0; k < 128; ++k) W2T[t*128 + k] = f2b(w_2[k*128 + t]);
  }
}

// ADJB[b][e][n] = u8(adj); ADJT[b][n][e] = u8(adj[b][e][n])
__global__ void k_prep(const float* __restrict__ adj,
                       unsigned char* __restrict__ ADJB, unsigned char* __restrict__ ADJT)
{
  __shared__ unsigned char tile[64][68];
  int b  = blockIdx.z;
  int e0 = blockIdx.y * 64;
  int n0 = blockIdx.x * 64;
  int t  = threadIdx.x;                 // 256
  int lr = t >> 2, lc0 = (t & 3) * 16;
  const float* src = adj + ((long)b*NE_ + e0 + lr)*NN_ + n0 + lc0;
  u8x16 ov;
  #pragma unroll
  for (int j = 0; j < 16; j += 4) {
    f32x4 v = *(const f32x4*)(src + j);
    #pragma unroll
    for (int k = 0; k < 4; ++k) {
      unsigned char u = (v[k] != 0.f) ? 1 : 0;
      ov[j+k] = u; tile[lr][lc0+j+k] = u;
    }
  }
  *(u8x16*)(ADJB + ((long)b*NE_ + e0 + lr)*NN_ + n0 + lc0) = ov;
  __syncthreads();
  u8x16 o;
  #pragma unroll
  for (int j = 0; j < 16; ++j) o[j] = tile[lc0 + j][lr];
  *(u8x16*)(ADJT + ((long)b*NN_ + n0 + lr)*NE_ + e0 + lc0) = o;
}

// fused: e1/f1 row-dots + w1=exp(e1) + YT[b][h][n] = bf16(w1*x) transposed write
template<int SRCBF>
__global__ void k_fproj(const float* __restrict__ srcF, const unsigned short* __restrict__ srcB,
                        const int* __restrict__ gitems,
                        const float* __restrict__ consts, int layer,
                        float* __restrict__ w1, float* __restrict__ f1,
                        unsigned short* __restrict__ YT)
{
  __shared__ float ce1s[128], cf1s[128];
  __shared__ __attribute__((aligned(16))) unsigned short T[64][132];
  int b = blockIdx.y, n0 = blockIdx.x * 64, t = threadIdx.x;  // 256
  if (t < 128) { ce1s[t] = consts[layer*384 + t]; cf1s[t] = consts[layer*384 + 128 + t]; }
  __syncthreads();
  int r = t >> 2, h0 = (t & 3) * 32;
  long row = (long)b*NN_ + n0 + r;
  float s0 = consts[768 + layer];
  float xv[32];
  if (SRCBF) {
    const unsigned short* sp = srcB + row*HID_ + h0;
    #pragma unroll
    for (int j = 0; j < 32; j += 8) {
      u16x8 v = *(const u16x8*)(sp + j);
      #pragma unroll
      for (int k = 0; k < 8; ++k) xv[j+k] = bfu(v[k]);
    }
  } else {
    const float* sp = srcF + (long)gitems[row]*HID_ + h0;
    #pragma unroll
    for (int j = 0; j < 32; j += 4) {
      f32x4 v = *(const f32x4*)(sp + j);
      #pragma unroll
      for (int k = 0; k < 4; ++k) xv[j+k] = v[k];
    }
  }
  float p1 = 0.f, p2 = 0.f;
  #pragma unroll
  for (int j = 0; j < 32; ++j) { p1 += xv[j]*ce1s[h0+j]; p2 += xv[j]*cf1s[h0+j]; }
  p1 += __shfl_xor(p1, 1, 4); p1 += __shfl_xor(p1, 2, 4);
  p2 += __shfl_xor(p2, 1, 4); p2 += __shfl_xor(p2, 2, 4);
  float z = p1 + s0; z = (z >= 0.f) ? z : ALPHA_*z;
  float w = __expf(z);
  if ((t & 3) == 0) { w1[row] = w; f1[row] = p2; }
  #pragma unroll
  for (int j = 0; j < 32; j += 4) {
    u16x4 o;
    #pragma unroll
    for (int k = 0; k < 4; ++k) o[k] = f2b(w * xv[j+k]);
    *(u16x4*)&T[r][h0+j] = o;
  }
  __syncthreads();
  int h = t >> 1, nh = (t & 1) * 32;
  unsigned short* dst = YT + ((long)b*HID_ + h)*NN_ + n0 + nh;
  #pragma unroll
  for (int j = 0; j < 32; j += 8) {
    u16x8 o;
    #pragma unroll
    for (int k = 0; k < 8; ++k) o[k] = T[nh+j+k][h];
    *(u16x8*)&dst[j] = o;
  }
}

// GEMM1: U = ADJB@Y (K=NN), double-buffered; epilogue: edge=U/den (opt @W_2), f2, ET transposed
// SM carve (ushort): As buf0 [0,2048) buf1 [2048,4096); Bs buf0 [4096,8192) buf1 [8192,12288)
// U reuse: [0, 8704)
template<int TRANSFER>
__global__ __launch_bounds__(256) void k_gemm_edge(
    const unsigned char* __restrict__ ADJB,
    const unsigned short* __restrict__ YT,
    const float* __restrict__ w1v,
    const float* __restrict__ consts, int layer,
    const unsigned short* __restrict__ W2T,
    unsigned short* __restrict__ ET,
    float* __restrict__ f2o)
{
  __shared__ __attribute__((aligned(16))) unsigned short SM[12288];
  __shared__ float dsum[64];
  const int id = blockIdx.x;
  const int b = id & 63;                 // same-batch blocks -> same XCD
  const long e0 = (long)(id >> 6) * 64;
  const int t = threadIdx.x;
  const int lane = t & 63;
  const int w = t >> 6, wm = w >> 1, wn = w & 1;
  const int r4 = t >> 2, c4 = t & 3;
  const int lr = lane & 15, g = lane >> 4;

  f32x4 acc[2][4];
  #pragma unroll
  for (int i = 0; i < 2; ++i)
    #pragma unroll
    for (int j = 0; j < 4; ++j) acc[i][j] = (f32x4){0.f,0.f,0.f,0.f};

  const unsigned char*  Ab = ADJB + ((long)b*NE_ + e0 + r4)*NN_;
  const unsigned short* Bb = YT + (long)b*HID_*NN_;
  const float*          wb = w1v + (long)b*NN_;

  unsigned long aw; u16x8 bv0, bv1; f32x4 wv0, wv1;
  float dot = 0.f;

  auto stage = [&](int kc) {
    aw  = *(const unsigned long*)(Ab + kc + c4*8);
    wv0 = *(const f32x4*)(wb + kc + c4*8);
    wv1 = *(const f32x4*)(wb + kc + c4*8 + 4);
    bv0 = *(const u16x8*)(Bb + (long)r4*NN_ + kc + c4*8);
    bv1 = *(const u16x8*)(Bb + (long)(64+r4)*NN_ + kc + c4*8);
  };
  auto commit = [&](int buf) {
    u16x8 av;
    #pragma unroll
    for (int j = 0; j < 8; ++j) {
      unsigned int by = (unsigned int)(aw >> (8*j)) & 0xffu;
      av[j] = by ? (unsigned short)0x3F80 : (unsigned short)0;
      float wj = (j < 4) ? wv0[j] : wv1[j-4];
      dot += by ? wj : 0.f;
    }
    *(u16x8*)&SM[buf*2048 + r4*32 + swz(r4,c4)*8] = av;
    *(u16x8*)&SM[4096 + buf*4096 + r4*32 + swz(r4,c4)*8] = bv0;
    *(u16x8*)&SM[4096 + buf*4096 + (64+r4)*32 + swz(64+r4,c4)*8] = bv1;
  };

  stage(0); commit(0);
  int cur = 0;
  const int NIT = NN_/32;
  for (int it = 0; it < NIT; ++it) {
    __syncthreads();
    if (it+1 < NIT) stage((it+1)*32);
    const unsigned short* AsB = &SM[cur*2048];
    const unsigned short* BsB = &SM[4096 + cur*4096];
    bf16x8 af[2], bfr[4];
    #pragma unroll
    for (int mt = 0; mt < 2; ++mt) {
      int r = wm*32 + mt*16 + lr;
      af[mt] = *(const bf16x8*)&AsB[r*32 + swz(r,g)*8];
    }
    #pragma unroll
    for (int nt = 0; nt < 4; ++nt) {
      int n = wn*64 + nt*16 + lr;
      bfr[nt] = *(const bf16x8*)&BsB[n*32 + swz(n,g)*8];
    }
    #pragma unroll
    for (int mt = 0; mt < 2; ++mt)
      #pragma unroll
      for (int nt = 0; nt < 4; ++nt)
        acc[mt][nt] = __builtin_amdgcn_mfma_f32_16x16x32_bf16(af[mt], bfr[nt], acc[mt][nt], 0, 0, 0);
    if (it+1 < NIT) { commit(cur^1); cur ^= 1; }
  }
  dot += __shfl_down(dot, 2, 4); dot += __shfl_down(dot, 1, 4);
  if ((lane & 3) == 0) dsum[r4] = dot;
  __syncthreads();   // frags read; dsum ready; SM reusable as U
  #pragma unroll
  for (int mt = 0; mt < 2; ++mt)
    #pragma unroll
    for (int nt = 0; nt < 4; ++nt) {
      int col = wn*64 + nt*16 + lr;
      #pragma unroll
      for (int q = 0; q < 4; ++q) {
        int rl = wm*32 + mt*16 + g*4 + q;
        SM[rl*136 + col] = f2b(acc[mt][nt][q] / dsum[rl]);
      }
    }
  __syncthreads();
  if (TRANSFER) {
    f32x4 acc2[2][4];
    #pragma unroll
    for (int i = 0; i < 2; ++i)
      #pragma unroll
      for (int j = 0; j < 4; ++j) acc2[i][j] = (f32x4){0.f,0.f,0.f,0.f};
    #pragma unroll
    for (int kc2 = 0; kc2 < 4; ++kc2) {
      bf16x8 af[2], bfr[4];
      #pragma unroll
      for (int mt = 0; mt < 2; ++mt) {
        int r = wm*32 + mt*16 + lr;
        af[mt] = *(const bf16x8*)&SM[r*136 + kc2*32 + g*8];
      }
      #pragma unroll
      for (int nt = 0; nt < 4; ++nt) {
        int n = wn*64 + nt*16 + lr;
        bfr[nt] = *(const bf16x8*)(W2T + n*128 + kc2*32 + g*8);
      }
      #pragma unroll
      for (int mt = 0; mt < 2; ++mt)
        #pragma unroll
        for (int nt = 0; nt < 4; ++nt)
          acc2[mt][nt] = __builtin_amdgcn_mfma_f32_16x16x32_bf16(af[mt], bfr[nt], acc2[mt][nt], 0, 0, 0);
    }
    __syncthreads();
    #pragma unroll
    for (int mt = 0; mt < 2; ++mt)
      #pragma unroll
      for (int nt = 0; nt < 4; ++nt) {
        int col = wn*64 + nt*16 + lr;
        #pragma unroll
        for (int q = 0; q < 4; ++q) {
          int rl = wm*32 + mt*16 + g*4 + q;
          SM[rl*136 + col] = f2b(acc2[mt][nt][q]);
        }
      }
    __syncthreads();
  }
  // f2 = edge . cf2
  {
    const float* cf2 = consts + layer*384 + 256;
    int r = t >> 2, h0 = (t & 3) * 32;
    float p = 0.f;
    #pragma unroll
    for (int j = 0; j < 32; ++j) p += bfu(SM[r*136 + h0 + j]) * cf2[h0 + j];
    p += __shfl_down(p, 2, 4); p += __shfl_down(p, 1, 4);
    if ((t & 3) == 0) f2o[(long)b*NE_ + e0 + r] = p;
  }
  // ET[b][h][e] transposed write
  {
    int h = t >> 1, eh = (t & 1) * 32;
    unsigned short* dst = ET + ((long)b*HID_ + h)*NE_ + e0 + eh;
    #pragma unroll
    for (int j = 0; j < 32; j += 8) {
      u16x8 o;
      #pragma unroll
      for (int k = 0; k < 8; ++k) o[k] = SM[(eh+j+k)*136 + h];
      *(u16x8*)&dst[j] = o;
    }
  }
}

// GEMM2: A[n][e] = adjT*exp(leaky(f1[n]+f2[e])) on the fly; C = (A@edge)/rowsum
// EPI 1: elu -> bf16 X2 ; EPI 2: wcount-weighted col-sum -> atomic pooled
template<int EPI>
__global__ __launch_bounds__(256, 2) void k_gemm_att(
    const unsigned char* __restrict__ ADJT,
    const unsigned short* __restrict__ ET,
    const float* __restrict__ f1v, const float* __restrict__ f2v,
    unsigned short* __restrict__ X2,
    const float* __restrict__ wcount, float* __restrict__ pooled)
{
  __shared__ __attribute__((aligned(16))) unsigned short SM[12288];
  __shared__ float dsum[64];
  __shared__ float colsum[128];
  const int id = blockIdx.x;
  const int b = id & 63;                 // same-batch blocks -> same XCD
  const long m0 = (long)(id >> 6) * 64;
  const int t = threadIdx.x;
  const int lane = t & 63;
  const int w = t >> 6, wm = w >> 1, wn = w & 1;
  const int r4 = t >> 2, c4 = t & 3;
  const int lr = lane & 15, g = lane >> 4;

  f32x4 acc[2][4];
  #pragma unroll
  for (int i = 0; i < 2; ++i)
    #pragma unroll
    for (int j = 0; j < 4; ++j) acc[i][j] = (f32x4){0.f,0.f,0.f,0.f};

  const float f1r = f1v[(long)b*NN_ + m0 + r4];
  const unsigned char*  Ab = ADJT + ((long)b*NN_ + m0 + r4)*NE_;
  const unsigned short* Bb = ET + (long)b*HID_*NE_;
  const float* f2p = f2v + (long)b*NE_;

  unsigned long aw; u16x8 bv0, bv1; f32x4 fv0, fv1;
  float dot = 0.f;

  auto stage = [&](int kc) {
    aw  = *(const unsigned long*)(Ab + kc + c4*8);
    fv0 = *(const f32x4*)(f2p + kc + c4*8);
    fv1 = *(const f32x4*)(f2p + kc + c4*8 + 4);
    bv0 = *(const u16x8*)(Bb + (long)r4*NE_ + kc + c4*8);
    bv1 = *(const u16x8*)(Bb + (long)(64+r4)*NE_ + kc + c4*8);
  };
  auto commit = [&](int buf) {
    u16x8 av;
    #pragma unroll
    for (int j = 0; j < 8; ++j) {
      unsigned int by = (unsigned int)(aw >> (8*j)) & 0xffu;
      float z = f1r + ((j < 4) ? fv0[j] : fv1[j-4]);
      z = (z >= 0.f) ? z : ALPHA_ * z;
      float wt = by ? __expf(z) : 0.f;
      unsigned short us = f2b(wt);
      av[j] = us; dot += bfu(us);
    }
    *(u16x8*)&SM[buf*2048 + r4*32 + swz(r4,c4)*8] = av;
    *(u16x8*)&SM[4096 + buf*4096 + r4*32 + swz(r4,c4)*8] = bv0;
    *(u16x8*)&SM[4096 + buf*4096 + (64+r4)*32 + swz(64+r4,c4)*8] = bv1;
  };

  stage(0); commit(0);
  int cur = 0;
  const int NIT = NE_/32;
  for (int it = 0; it < NIT; ++it) {
    __syncthreads();
    if (it+1 < NIT) stage((it+1)*32);
    const unsigned short* AsB = &SM[cur*2048];
    const unsigned short* BsB = &SM[4096 + cur*4096];
    bf16x8 af[2], bfr[4];
    #pragma unroll
    for (int mt = 0; mt < 2; ++mt) {
      int r = wm*32 + mt*16 + lr;
      af[mt] = *(const bf16x8*)&AsB[r*32 + swz(r,g)*8];
    }
    #pragma unroll
    for (int nt = 0; nt < 4; ++nt) {
      int n = wn*64 + nt*16 + lr;
      bfr[nt] = *(const bf16x8*)&BsB[n*32 + swz(n,g)*8];
    }
    #pragma unroll
    for (int mt = 0; mt < 2; ++mt)
      #pragma unroll
      for (int nt = 0; nt < 4; ++nt)
        acc[mt][nt] = __builtin_amdgcn_mfma_f32_16x16x32_bf16(af[mt], bfr[nt], acc[mt][nt], 0, 0, 0);
    if (it+1 < NIT) { commit(cur^1); cur ^= 1; }
  }
  dot += __shfl_down(dot, 2, 4); dot += __shfl_down(dot, 1, 4);
  if ((lane & 3) == 0) dsum[r4] = dot;
  if (EPI == 2 && t < 128) colsum[t] = 0.f;
  __syncthreads();

  if (EPI == 1) {
    #pragma unroll
    for (int mt = 0; mt < 2; ++mt)
      #pragma unroll
      for (int nt = 0; nt < 4; ++nt) {
        int col = wn*64 + nt*16 + lr;
        #pragma unroll
        for (int q = 0; q < 4; ++q) {
          int rl = wm*32 + mt*16 + g*4 + q;
          float v = acc[mt][nt][q] / dsum[rl];
          v = (v > 0.f) ? v : expm1f(v);
          X2[(long)b*NN_*HID_ + (m0 + rl)*HID_ + col] = f2b(v);
        }
      }
  } else {
    float psum[4] = {0.f, 0.f, 0.f, 0.f};
    #pragma unroll
    for (int mt = 0; mt < 2; ++mt)
      #pragma unroll
      for (int q = 0; q < 4; ++q) {
        int rl = wm*32 + mt*16 + g*4 + q;
        float wc = wcount[(long)b*NN_ + m0 + rl];
        float inv = wc / dsum[rl];
        #pragma unroll
        for (int nt = 0; nt < 4; ++nt) psum[nt] += inv * acc[mt][nt][q];
      }
    #pragma unroll
    for (int nt = 0; nt < 4; ++nt) atomicAdd(&colsum[wn*64 + nt*16 + lr], psum[nt]);
    __syncthreads();
    if (t < 128) atomicAdd(&pooled[(long)b*HID_ + t], colsum[t]);
  }
}

__global__ void k_zero(float* __restrict__ p, int n)
{
  int i = blockIdx.x*256 + threadIdx.x;
  if (i < n) p[i] = 0.f;
}

__global__ void k_wcount(const int* __restrict__ alias, const float* __restrict__ masks,
                         float* __restrict__ wcount, float* __restrict__ msum)
{
  int b = blockIdx.x, t = threadIdx.x;   // 512
  float m = masks[b*L_ + t];
  int idx = alias[b*L_ + t];
  atomicAdd(&wcount[(long)b*NN_ + idx], m*m);
  float s = m;
  #pragma unroll
  for (int sh = 32; sh > 0; sh >>= 1) s += __shfl_down(s, sh);
  __shared__ float red[8];
  if ((t & 63) == 0) red[t >> 6] = s;
  __syncthreads();
  if (t == 0) { float tot = 0.f; for (int i = 0; i < 8; ++i) tot += red[i]; msum[b] = tot; }
}

__global__ void k_ln(const float* __restrict__ pooled, const float* __restrict__ msum,
                     const float* __restrict__ ln_g, const float* __restrict__ ln_b,
                     float* __restrict__ out)
{
  int b = blockIdx.x, t = threadIdx.x;   // 128
  __shared__ float sr[2];
  float bv = pooled[b*HID_ + t] / msum[b];
  int lane = t & 63;
  float p = bv;
  #pragma unroll
  for (int s = 32; s > 0; s >>= 1) p += __shfl_xor(p, s);
  if (lane == 0) sr[t >> 6] = p;
  __syncthreads();
  float mu = (sr[0] + sr[1]) * (1.f / HID_);
  float dv = bv - mu;
  p = dv * dv;
  #pragma unroll
  for (int s = 32; s > 0; s >>= 1) p += __shfl_xor(p, s);
  __syncthreads();
  if (lane == 0) sr[t >> 6] = p;
  __syncthreads();
  float var = (sr[0] + sr[1]) * (1.f / HID_);
  out[b*HID_ + t] = dv / sqrtf(var + 1e-6f) * ln_g[t] + ln_b[t];
}

extern "C" void kernel_launch(void* const* d_in, const int* in_sizes, int n_in,
                              void* d_out, int out_size, void* d_ws, size_t ws_size,
                              hipStream_t stream)
{
  const int*   items = (const int*)d_in[0];
  const int*   alias = (const int*)d_in[1];
  const float* masks = (const float*)d_in[2];
  const float* adj   = (const float*)d_in[3];
  const float* emb   = (const float*)d_in[4];
  const float* w2_1  = (const float*)d_in[5];
  const float* w3_1  = (const float*)d_in[6];
  const float* a_1   = (const float*)d_in[7];
  const float* a2_1  = (const float*)d_in[8];
  const float* wc_1  = (const float*)d_in[9];
  const float* w_2   = (const float*)d_in[10];
  const float* w2_2  = (const float*)d_in[11];
  const float* w3_2  = (const float*)d_in[12];
  const float* a_2   = (const float*)d_in[13];
  const float* a2_2  = (const float*)d_in[14];
  const float* wc_2  = (const float*)d_in[15];
  const float* ln_g  = (const float*)d_in[16];
  const float* ln_b  = (const float*)d_in[17];
  float* out = (float*)d_out;

  char* ws = (char*)d_ws;
  size_t off = 0;
  auto alloc = [&](size_t bytes) -> void* {
    void* p = ws + off; off += (bytes + 255) / 256 * 256; return p;
  };
  unsigned char*  ADJB = (unsigned char*) alloc((size_t)B_*NE_*NN_);
  unsigned char*  ADJT = (unsigned char*) alloc((size_t)B_*NN_*NE_);
  unsigned short* YT   = (unsigned short*)alloc((size_t)B_*HID_*NN_*2);
  unsigned short* ET   = (unsigned short*)alloc((size_t)B_*HID_*NE_*2);
  unsigned short* X2BF = (unsigned short*)alloc((size_t)B_*NN_*HID_*2);
  float* wcount= (float*)alloc((size_t)B_*NN_*4);      // contiguous with pooled
  float* pooled= (float*)alloc((size_t)B_*HID_*4);
  float* w1    = (float*)alloc((size_t)B_*NN_*4);
  float* f1    = (float*)alloc((size_t)B_*NN_*4);
  float* f2    = (float*)alloc((size_t)B_*NE_*4);
  float* msum  = (float*)alloc(B_*4);
  float* consts= (float*)alloc(772*4);
  unsigned short* W2T = (unsigned short*)alloc((size_t)HID_*HID_*2);
  if (off > ws_size) return;

  const int kZeroN = B_*NN_ + B_*HID_;    // wcount + pooled

  k_consts<<<9, 128, 0, stream>>>(w2_1, w3_1, a_1, a2_1, wc_1, w2_2, w3_2, a_2, a2_2, wc_2,
                                  w_2, consts, W2T);
  k_zero<<<(kZeroN + 255)/256, 256, 0, stream>>>(wcount, kZeroN);
  k_wcount<<<B_, L_, 0, stream>>>(alias, masks, wcount, msum);
  k_prep<<<dim3(NN_/64, NE_/64, B_), 256, 0, stream>>>(adj, ADJB, ADJT);

  // ---------------- layer 1 ----------------
  k_fproj<0><<<dim3(NN_/64, B_), 256, 0, stream>>>(emb, nullptr, items, consts, 0, w1, f1, YT);
  k_gemm_edge<0><<<B_*(NE_/64), 256, 0, stream>>>(ADJB, YT, w1, consts, 0, W2T, ET, f2);
  k_gemm_att<1><<<B_*(NN_/64), 256, 0, stream>>>(ADJT, ET, f1, f2, X2BF, nullptr, nullptr);

  // ---------------- layer 2 ----------------
  k_fproj<1><<<dim3(NN_/64, B_), 256, 0, stream>>>(nullptr, X2BF, nullptr, consts, 1, w1, f1, YT);
  k_gemm_edge<1><<<B_*(NE_/64), 256, 0, stream>>>(ADJB, YT, w1, consts, 1, W2T, ET, f2);
  k_gemm_att<2><<<B_*(NN_/64), 256, 0, stream>>>(ADJT, ET, f1, f2, nullptr, wcount, pooled);

  // ---------------- layernorm ----------------
  k_ln<<<B_, HID_, 0, stream>>>(pooled, msum, ln_g, ln_b, out);
}

// Round 7
// 133.641 us; speedup vs baseline: 4.8423x; 1.0500x over previous
//
#include <hip/hip_runtime.h>
#include <hip/hip_bf16.h>

typedef __hip_bfloat16 bf16;
typedef __attribute__((ext_vector_type(8))) unsigned short u16x8;
typedef __attribute__((ext_vector_type(4))) unsigned short u16x4;
typedef __attribute__((ext_vector_type(4))) float f32x4;
typedef __attribute__((ext_vector_type(8))) short bf16x8;

#define B_   64
#define NE_  256
#define NN_  1024
#define L_   512
#define HID_ 128
#define ALPHA_ 0.2f

__device__ __forceinline__ float bfu(unsigned short u){
  unsigned int x = ((unsigned int)u) << 16;
  union { unsigned int i; float f; } c; c.i = x; return c.f;
}
__device__ __forceinline__ unsigned short f2b(float f){
  bf16 h = __float2bfloat16(f);
  union { bf16 b; unsigned short u; } c; c.b = h; return c.u;
}
// chunk swizzle: involution in c for fixed r; spreads frag reads to <=2-way
__device__ __forceinline__ int swz(int r, int c){ return (c ^ (r & 3) ^ ((r >> 2) & 3)) & 3; }

// consts layout (floats): [0:128) ce1_1, [128:256) cf1_1, [256:384) cf2_1,
// [384:512) ce1_2, [512:640) cf1_2, [640:768) cf2_2, [768] s0_1, [769] s0_2
__global__ void k_consts(const float* w2_1, const float* w3_1,
                         const float* a_1, const float* a2_1, const float* wc_1,
                         const float* w2_2, const float* w3_2,
                         const float* a_2, const float* a2_2, const float* wc_2,
                         const float* w_2,
                         float* consts, unsigned short* W2T)
{
  int blk = blockIdx.x, t = threadIdx.x; // 128 threads
  __shared__ float red[128];
  if (blk < 6) {
    const float* M; const float* v;
    switch (blk) {
      case 0: M = w2_1; v = a_1  + 128; break;
      case 1: M = w2_1; v = a2_1;       break;
      case 2: M = w3_1; v = a2_1 + 128; break;
      case 3: M = w2_2; v = a_2  + 128; break;
      case 4: M = w2_2; v = a2_2;       break;
      default: M = w3_2; v = a2_2 + 128; break;
    }
    float acc = 0.f;
    for (int o = 0; o < 128; ++o) acc += M[t*128 + o] * v[o];
    consts[blk*128 + t] = acc;
  } else if (blk < 8) {
    const float* wc = (blk == 6) ? wc_1 : wc_2;
    const float* a  = (blk == 6) ? a_1  : a_2;
    red[t] = wc[t] * a[t];
    __syncthreads();
    for (int s = 64; s > 0; s >>= 1) { if (t < s) red[t] += red[t + s]; __syncthreads(); }
    if (t == 0) consts[768 + (blk - 6)] = red[0];
  } else {
    // W2T[h][k] = w_2[k][h]
    for (int k = 0; k < 128; ++k) W2T[t*128 + k] = f2b(w_2[k*128 + t]);
  }
}

// bit-packed: ADJBb[b][e] row = NN/64 ulongs; ADJTb[b][n] row = NE/64 ulongs
__global__ void k_prep(const float* __restrict__ adj,
                       unsigned long long* __restrict__ ADJBb,
                       unsigned long long* __restrict__ ADJTb)
{
  __shared__ unsigned char tile[64][68];
  __shared__ unsigned short pa[64][4];
  __shared__ unsigned short pt[64][4];
  int b  = blockIdx.z;
  int e0 = blockIdx.y * 64;
  int n0 = blockIdx.x * 64;
  int t  = threadIdx.x;                 // 256
  int lr = t >> 2, lc0 = (t & 3) * 16;
  const float* src = adj + ((long)b*NE_ + e0 + lr)*NN_ + n0 + lc0;
  unsigned int mA = 0;
  #pragma unroll
  for (int j = 0; j < 16; j += 4) {
    f32x4 v = *(const f32x4*)(src + j);
    #pragma unroll
    for (int k = 0; k < 4; ++k) {
      unsigned char u = (v[k] != 0.f) ? 1 : 0;
      tile[lr][lc0+j+k] = u;
      mA |= ((unsigned int)u) << (j+k);
    }
  }
  pa[lr][t & 3] = (unsigned short)mA;
  __syncthreads();
  unsigned int mT = 0;
  #pragma unroll
  for (int j = 0; j < 16; ++j) mT |= ((unsigned int)tile[lc0 + j][lr]) << j;
  pt[lr][t & 3] = (unsigned short)mT;
  __syncthreads();
  if (t < 64) {
    unsigned long long wA = (unsigned long long)pa[t][0]
                          | ((unsigned long long)pa[t][1] << 16)
                          | ((unsigned long long)pa[t][2] << 32)
                          | ((unsigned long long)pa[t][3] << 48);
    ADJBb[((long)b*NE_ + e0 + t)*(NN_/64) + (n0 >> 6)] = wA;
    unsigned long long wT = (unsigned long long)pt[t][0]
                          | ((unsigned long long)pt[t][1] << 16)
                          | ((unsigned long long)pt[t][2] << 32)
                          | ((unsigned long long)pt[t][3] << 48);
    ADJTb[((long)b*NN_ + n0 + t)*(NE_/64) + (e0 >> 6)] = wT;
  }
}

// layer-1 fused: e1/f1 row-dots + w1=exp(e1) + YT[b][h][n] = bf16(w1*x) transposed
__global__ void k_fproj(const float* __restrict__ emb, const int* __restrict__ gitems,
                        const float* __restrict__ consts,
                        float* __restrict__ w1, float* __restrict__ f1,
                        unsigned short* __restrict__ YT)
{
  __shared__ float ce1s[128], cf1s[128];
  __shared__ __attribute__((aligned(16))) unsigned short T[64][132];
  int b = blockIdx.y, n0 = blockIdx.x * 64, t = threadIdx.x;  // 256
  if (t < 128) { ce1s[t] = consts[t]; cf1s[t] = consts[128 + t]; }
  __syncthreads();
  int r = t >> 2, h0 = (t & 3) * 32;
  long row = (long)b*NN_ + n0 + r;
  float s0 = consts[768];
  float xv[32];
  const float* sp = emb + (long)gitems[row]*HID_ + h0;
  #pragma unroll
  for (int j = 0; j < 32; j += 4) {
    f32x4 v = *(const f32x4*)(sp + j);
    #pragma unroll
    for (int k = 0; k < 4; ++k) xv[j+k] = v[k];
  }
  float p1 = 0.f, p2 = 0.f;
  #pragma unroll
  for (int j = 0; j < 32; ++j) { p1 += xv[j]*ce1s[h0+j]; p2 += xv[j]*cf1s[h0+j]; }
  p1 += __shfl_xor(p1, 1, 4); p1 += __shfl_xor(p1, 2, 4);
  p2 += __shfl_xor(p2, 1, 4); p2 += __shfl_xor(p2, 2, 4);
  float z = p1 + s0; z = (z >= 0.f) ? z : ALPHA_*z;
  float w = __expf(z);
  if ((t & 3) == 0) { w1[row] = w; f1[row] = p2; }
  #pragma unroll
  for (int j = 0; j < 32; j += 4) {
    u16x4 o;
    #pragma unroll
    for (int k = 0; k < 4; ++k) o[k] = f2b(w * xv[j+k]);
    *(u16x4*)&T[r][h0+j] = o;
  }
  __syncthreads();
  int h = t >> 1, nh = (t & 1) * 32;
  unsigned short* dst = YT + ((long)b*HID_ + h)*NN_ + n0 + nh;
  #pragma unroll
  for (int j = 0; j < 32; j += 8) {
    u16x8 o;
    #pragma unroll
    for (int k = 0; k < 8; ++k) o[k] = T[nh+j+k][h];
    *(u16x8*)&dst[j] = o;
  }
}

// GEMM1: U = adj@Y (K=NN, bit A), double-buffered; epilogue: edge=U/den (opt @W_2), f2, ET^T
template<int TRANSFER>
__global__ __launch_bounds__(256) void k_gemm_edge(
    const unsigned char* __restrict__ ADJ8,
    const unsigned short* __restrict__ YT,
    const float* __restrict__ w1v,
    const float* __restrict__ consts, int layer,
    const unsigned short* __restrict__ W2T,
    unsigned short* __restrict__ ET,
    float* __restrict__ f2o)
{
  __shared__ __attribute__((aligned(16))) unsigned short SM[12288];
  __shared__ float dsum[64];
  const int id = blockIdx.x;
  const int b = id & 63;                 // same-batch blocks -> same XCD
  const long e0 = (long)(id >> 6) * 64;
  const int t = threadIdx.x;
  const int lane = t & 63;
  const int w = t >> 6, wm = w >> 1, wn = w & 1;
  const int r4 = t >> 2, c4 = t & 3;
  const int lr = lane & 15, g = lane >> 4;

  f32x4 acc[2][4];
  #pragma unroll
  for (int i = 0; i < 2; ++i)
    #pragma unroll
    for (int j = 0; j < 4; ++j) acc[i][j] = (f32x4){0.f,0.f,0.f,0.f};

  const unsigned char*  Ab = ADJ8 + ((long)b*NE_ + e0 + r4)*(NN_ >> 3);
  const unsigned short* Bb = YT + (long)b*HID_*NN_;
  const float*          wb = w1v + (long)b*NN_;

  unsigned int ab; u16x8 bv0, bv1; f32x4 wv0, wv1;
  float dot = 0.f;

  auto stage = [&](int kc) {
    ab  = Ab[(kc >> 3) + c4];
    wv0 = *(const f32x4*)(wb + kc + c4*8);
    wv1 = *(const f32x4*)(wb + kc + c4*8 + 4);
    bv0 = *(const u16x8*)(Bb + (long)r4*NN_ + kc + c4*8);
    bv1 = *(const u16x8*)(Bb + (long)(64+r4)*NN_ + kc + c4*8);
  };
  auto commit = [&](int buf) {
    u16x8 av;
    #pragma unroll
    for (int j = 0; j < 8; ++j) {
      unsigned int bit = (ab >> j) & 1u;
      av[j] = bit ? (unsigned short)0x3F80 : (unsigned short)0;
      float wj = (j < 4) ? wv0[j] : wv1[j-4];
      dot += bit ? wj : 0.f;
    }
    *(u16x8*)&SM[buf*2048 + r4*32 + swz(r4,c4)*8] = av;
    *(u16x8*)&SM[4096 + buf*4096 + r4*32 + swz(r4,c4)*8] = bv0;
    *(u16x8*)&SM[4096 + buf*4096 + (64+r4)*32 + swz(64+r4,c4)*8] = bv1;
  };

  stage(0); commit(0);
  int cur = 0;
  const int NIT = NN_/32;
  for (int it = 0; it < NIT; ++it) {
    __syncthreads();
    if (it+1 < NIT) stage((it+1)*32);
    const unsigned short* AsB = &SM[cur*2048];
    const unsigned short* BsB = &SM[4096 + cur*4096];
    bf16x8 af[2], bfr[4];
    #pragma unroll
    for (int mt = 0; mt < 2; ++mt) {
      int r = wm*32 + mt*16 + lr;
      af[mt] = *(const bf16x8*)&AsB[r*32 + swz(r,g)*8];
    }
    #pragma unroll
    for (int nt = 0; nt < 4; ++nt) {
      int n = wn*64 + nt*16 + lr;
      bfr[nt] = *(const bf16x8*)&BsB[n*32 + swz(n,g)*8];
    }
    #pragma unroll
    for (int mt = 0; mt < 2; ++mt)
      #pragma unroll
      for (int nt = 0; nt < 4; ++nt)
        acc[mt][nt] = __builtin_amdgcn_mfma_f32_16x16x32_bf16(af[mt], bfr[nt], acc[mt][nt], 0, 0, 0);
    if (it+1 < NIT) { commit(cur^1); cur ^= 1; }
  }
  dot += __shfl_down(dot, 2, 4); dot += __shfl_down(dot, 1, 4);
  if ((lane & 3) == 0) dsum[r4] = dot;
  __syncthreads();   // frags read; dsum ready; SM reusable as U
  #pragma unroll
  for (int mt = 0; mt < 2; ++mt)
    #pragma unroll
    for (int nt = 0; nt < 4; ++nt) {
      int col = wn*64 + nt*16 + lr;
      #pragma unroll
      for (int q = 0; q < 4; ++q) {
        int rl = wm*32 + mt*16 + g*4 + q;
        SM[rl*136 + col] = f2b(acc[mt][nt][q] / dsum[rl]);
      }
    }
  __syncthreads();
  if (TRANSFER) {
    f32x4 acc2[2][4];
    #pragma unroll
    for (int i = 0; i < 2; ++i)
      #pragma unroll
      for (int j = 0; j < 4; ++j) acc2[i][j] = (f32x4){0.f,0.f,0.f,0.f};
    #pragma unroll
    for (int kc2 = 0; kc2 < 4; ++kc2) {
      bf16x8 af[2], bfr[4];
      #pragma unroll
      for (int mt = 0; mt < 2; ++mt) {
        int r = wm*32 + mt*16 + lr;
        af[mt] = *(const bf16x8*)&SM[r*136 + kc2*32 + g*8];
      }
      #pragma unroll
      for (int nt = 0; nt < 4; ++nt) {
        int n = wn*64 + nt*16 + lr;
        bfr[nt] = *(const bf16x8*)(W2T + n*128 + kc2*32 + g*8);
      }
      #pragma unroll
      for (int mt = 0; mt < 2; ++mt)
        #pragma unroll
        for (int nt = 0; nt < 4; ++nt)
          acc2[mt][nt] = __builtin_amdgcn_mfma_f32_16x16x32_bf16(af[mt], bfr[nt], acc2[mt][nt], 0, 0, 0);
    }
    __syncthreads();
    #pragma unroll
    for (int mt = 0; mt < 2; ++mt)
      #pragma unroll
      for (int nt = 0; nt < 4; ++nt) {
        int col = wn*64 + nt*16 + lr;
        #pragma unroll
        for (int q = 0; q < 4; ++q) {
          int rl = wm*32 + mt*16 + g*4 + q;
          SM[rl*136 + col] = f2b(acc2[mt][nt][q]);
        }
      }
    __syncthreads();
  }
  // f2 = edge . cf2
  {
    const float* cf2 = consts + layer*384 + 256;
    int r = t >> 2, h0 = (t & 3) * 32;
    float p = 0.f;
    #pragma unroll
    for (int j = 0; j < 32; ++j) p += bfu(SM[r*136 + h0 + j]) * cf2[h0 + j];
    p += __shfl_down(p, 2, 4); p += __shfl_down(p, 1, 4);
    if ((t & 3) == 0) f2o[(long)b*NE_ + e0 + r] = p;
  }
  // ET[b][h][e] transposed write
  {
    int h = t >> 1, eh = (t & 1) * 32;
    unsigned short* dst = ET + ((long)b*HID_ + h)*NE_ + e0 + eh;
    #pragma unroll
    for (int j = 0; j < 32; j += 8) {
      u16x8 o;
      #pragma unroll
      for (int k = 0; k < 8; ++k) o[k] = SM[(eh+j+k)*136 + h];
      *(u16x8*)&dst[j] = o;
    }
  }
}

// GEMM2: A[n][e] = bit*exp(leaky(f1[n]+f2[e])) on the fly; C = (A@edge)/rowsum
// EPI 1: elu -> x2, fused next-layer proj: w1/f1 out + YT out (transposed, w1-scaled)
// EPI 2: wcount-weighted col-sum -> atomic pooled
template<int EPI>
__global__ __launch_bounds__(256, 2) void k_gemm_att(
    const unsigned char* __restrict__ ADJ8,
    const unsigned short* __restrict__ ET,
    const float* __restrict__ f1v, const float* __restrict__ f2v,
    const float* __restrict__ consts,
    unsigned short* __restrict__ YTout, float* __restrict__ w1o, float* __restrict__ f1o,
    const float* __restrict__ wcount, float* __restrict__ pooled)
{
  __shared__ __attribute__((aligned(16))) unsigned short SM[12288];
  __shared__ float dsum[64];
  __shared__ float colsum[128];
  __shared__ float wrow[64];
  const int id = blockIdx.x;
  const int b = id & 63;                 // same-batch blocks -> same XCD
  const long m0 = (long)(id >> 6) * 64;
  const int t = threadIdx.x;
  const int lane = t & 63;
  const int w = t >> 6, wm = w >> 1, wn = w & 1;
  const int r4 = t >> 2, c4 = t & 3;
  const int lr = lane & 15, g = lane >> 4;

  f32x4 acc[2][4];
  #pragma unroll
  for (int i = 0; i < 2; ++i)
    #pragma unroll
    for (int j = 0; j < 4; ++j) acc[i][j] = (f32x4){0.f,0.f,0.f,0.f};

  const float f1r = f1v[(long)b*NN_ + m0 + r4];
  const unsigned char*  Ab = ADJ8 + ((long)b*NN_ + m0 + r4)*(NE_ >> 3);
  const unsigned short* Bb = ET + (long)b*HID_*NE_;
  const float* f2p = f2v + (long)b*NE_;

  unsigned int ab; u16x8 bv0, bv1; f32x4 fv0, fv1;
  float dot = 0.f;

  auto stage = [&](int kc) {
    ab  = Ab[(kc >> 3) + c4];
    fv0 = *(const f32x4*)(f2p + kc + c4*8);
    fv1 = *(const f32x4*)(f2p + kc + c4*8 + 4);
    bv0 = *(const u16x8*)(Bb + (long)r4*NE_ + kc + c4*8);
    bv1 = *(const u16x8*)(Bb + (long)(64+r4)*NE_ + kc + c4*8);
  };
  auto commit = [&](int buf) {
    u16x8 av;
    #pragma unroll
    for (int j = 0; j < 8; ++j) {
      unsigned int bit = (ab >> j) & 1u;
      float z = f1r + ((j < 4) ? fv0[j] : fv1[j-4]);
      z = (z >= 0.f) ? z : ALPHA_ * z;
      float wt = bit ? __expf(z) : 0.f;
      unsigned short us = f2b(wt);
      av[j] = us; dot += bfu(us);
    }
    *(u16x8*)&SM[buf*2048 + r4*32 + swz(r4,c4)*8] = av;
    *(u16x8*)&SM[4096 + buf*4096 + r4*32 + swz(r4,c4)*8] = bv0;
    *(u16x8*)&SM[4096 + buf*4096 + (64+r4)*32 + swz(64+r4,c4)*8] = bv1;
  };

  stage(0); commit(0);
  int cur = 0;
  const int NIT = NE_/32;
  for (int it = 0; it < NIT; ++it) {
    __syncthreads();
    if (it+1 < NIT) stage((it+1)*32);
    const unsigned short* AsB = &SM[cur*2048];
    const unsigned short* BsB = &SM[4096 + cur*4096];
    bf16x8 af[2], bfr[4];
    #pragma unroll
    for (int mt = 0; mt < 2; ++mt) {
      int r = wm*32 + mt*16 + lr;
      af[mt] = *(const bf16x8*)&AsB[r*32 + swz(r,g)*8];
    }
    #pragma unroll
    for (int nt = 0; nt < 4; ++nt) {
      int n = wn*64 + nt*16 + lr;
      bfr[nt] = *(const bf16x8*)&BsB[n*32 + swz(n,g)*8];
    }
    #pragma unroll
    for (int mt = 0; mt < 2; ++mt)
      #pragma unroll
      for (int nt = 0; nt < 4; ++nt)
        acc[mt][nt] = __builtin_amdgcn_mfma_f32_16x16x32_bf16(af[mt], bfr[nt], acc[mt][nt], 0, 0, 0);
    if (it+1 < NIT) { commit(cur^1); cur ^= 1; }
  }
  dot += __shfl_down(dot, 2, 4); dot += __shfl_down(dot, 1, 4);
  if ((lane & 3) == 0) dsum[r4] = dot;
  if (EPI == 2 && t < 128) colsum[t] = 0.f;
  __syncthreads();

  if (EPI == 1) {
    // x2 = elu(node) -> LDS U[64][136]
    #pragma unroll
    for (int mt = 0; mt < 2; ++mt)
      #pragma unroll
      for (int nt = 0; nt < 4; ++nt) {
        int col = wn*64 + nt*16 + lr;
        #pragma unroll
        for (int q = 0; q < 4; ++q) {
          int rl = wm*32 + mt*16 + g*4 + q;
          float v = acc[mt][nt][q] / dsum[rl];
          v = (v > 0.f) ? v : expm1f(v);
          SM[rl*136 + col] = f2b(v);
        }
      }
    __syncthreads();
    // fused layer-2 proj: row dots with ce1_2/cf1_2
    {
      const float* ce1 = consts + 384;
      const float* cf1 = consts + 512;
      int r = t >> 2, h0 = (t & 3) * 32;
      float p1 = 0.f, p2 = 0.f;
      #pragma unroll
      for (int j = 0; j < 32; ++j) {
        float xv = bfu(SM[r*136 + h0 + j]);
        p1 += xv * ce1[h0 + j];
        p2 += xv * cf1[h0 + j];
      }
      p1 += __shfl_down(p1, 2, 4); p1 += __shfl_down(p1, 1, 4);
      p2 += __shfl_down(p2, 2, 4); p2 += __shfl_down(p2, 1, 4);
      if ((t & 3) == 0) {
        float z = p1 + consts[769];
        z = (z >= 0.f) ? z : ALPHA_ * z;
        float wv = __expf(z);
        wrow[r] = wv;
        w1o[(long)b*NN_ + m0 + r] = wv;
        f1o[(long)b*NN_ + m0 + r] = p2;
      }
    }
    __syncthreads();
    // YT[b][h][n] = bf16(w1*x2) transposed write
    {
      int h = t >> 1, nh = (t & 1) * 32;
      unsigned short* dst = YTout + ((long)b*HID_ + h)*NN_ + m0 + nh;
      #pragma unroll
      for (int j = 0; j < 32; j += 8) {
        u16x8 o;
        #pragma unroll
        for (int k = 0; k < 8; ++k) {
          int rr = nh + j + k;
          o[k] = f2b(wrow[rr] * bfu(SM[rr*136 + h]));
        }
        *(u16x8*)&dst[j] = o;
      }
    }
  } else {
    float psum[4] = {0.f, 0.f, 0.f, 0.f};
    #pragma unroll
    for (int mt = 0; mt < 2; ++mt)
      #pragma unroll
      for (int q = 0; q < 4; ++q) {
        int rl = wm*32 + mt*16 + g*4 + q;
        float wc = wcount[(long)b*NN_ + m0 + rl];
        float inv = wc / dsum[rl];
        #pragma unroll
        for (int nt = 0; nt < 4; ++nt) psum[nt] += inv * acc[mt][nt][q];
      }
    #pragma unroll
    for (int nt = 0; nt < 4; ++nt) atomicAdd(&colsum[wn*64 + nt*16 + lr], psum[nt]);
    __syncthreads();
    if (t < 128) atomicAdd(&pooled[(long)b*HID_ + t], colsum[t]);
  }
}

__global__ void k_zero(float* __restrict__ p, int n)
{
  int i = blockIdx.x*256 + threadIdx.x;
  if (i < n) p[i] = 0.f;
}

__global__ void k_wcount(const int* __restrict__ alias, const float* __restrict__ masks,
                         float* __restrict__ wcount, float* __restrict__ msum)
{
  int b = blockIdx.x, t = threadIdx.x;   // 512
  float m = masks[b*L_ + t];
  int idx = alias[b*L_ + t];
  atomicAdd(&wcount[(long)b*NN_ + idx], m*m);
  float s = m;
  #pragma unroll
  for (int sh = 32; sh > 0; sh >>= 1) s += __shfl_down(s, sh);
  __shared__ float red[8];
  if ((t & 63) == 0) red[t >> 6] = s;
  __syncthreads();
  if (t == 0) { float tot = 0.f; for (int i = 0; i < 8; ++i) tot += red[i]; msum[b] = tot; }
}

__global__ void k_ln(const float* __restrict__ pooled, const float* __restrict__ msum,
                     const float* __restrict__ ln_g, const float* __restrict__ ln_b,
                     float* __restrict__ out)
{
  int b = blockIdx.x, t = threadIdx.x;   // 128
  __shared__ float sr[2];
  float bv = pooled[b*HID_ + t] / msum[b];
  int lane = t & 63;
  float p = bv;
  #pragma unroll
  for (int s = 32; s > 0; s >>= 1) p += __shfl_xor(p, s);
  if (lane == 0) sr[t >> 6] = p;
  __syncthreads();
  float mu = (sr[0] + sr[1]) * (1.f / HID_);
  float dv = bv - mu;
  p = dv * dv;
  #pragma unroll
  for (int s = 32; s > 0; s >>= 1) p += __shfl_xor(p, s);
  __syncthreads();
  if (lane == 0) sr[t >> 6] = p;
  __syncthreads();
  float var = (sr[0] + sr[1]) * (1.f / HID_);
  out[b*HID_ + t] = dv / sqrtf(var + 1e-6f) * ln_g[t] + ln_b[t];
}

extern "C" void kernel_launch(void* const* d_in, const int* in_sizes, int n_in,
                              void* d_out, int out_size, void* d_ws, size_t ws_size,
                              hipStream_t stream)
{
  const int*   items = (const int*)d_in[0];
  const int*   alias = (const int*)d_in[1];
  const float* masks = (const float*)d_in[2];
  const float* adj   = (const float*)d_in[3];
  const float* emb   = (const float*)d_in[4];
  const float* w2_1  = (const float*)d_in[5];
  const float* w3_1  = (const float*)d_in[6];
  const float* a_1   = (const float*)d_in[7];
  const float* a2_1  = (const float*)d_in[8];
  const float* wc_1  = (const float*)d_in[9];
  const float* w_2   = (const float*)d_in[10];
  const float* w2_2  = (const float*)d_in[11];
  const float* w3_2  = (const float*)d_in[12];
  const float* a_2   = (const float*)d_in[13];
  const float* a2_2  = (const float*)d_in[14];
  const float* wc_2  = (const float*)d_in[15];
  const float* ln_g  = (const float*)d_in[16];
  const float* ln_b  = (const float*)d_in[17];
  float* out = (float*)d_out;

  char* ws = (char*)d_ws;
  size_t off = 0;
  auto alloc = [&](size_t bytes) -> void* {
    void* p = ws + off; off += (bytes + 255) / 256 * 256; return p;
  };
  unsigned long long* ADJBb = (unsigned long long*)alloc((size_t)B_*NE_*(NN_/8));
  unsigned long long* ADJTb = (unsigned long long*)alloc((size_t)B_*NN_*(NE_/8));
  unsigned short* YT   = (unsigned short*)alloc((size_t)B_*HID_*NN_*2);
  unsigned short* ET   = (unsigned short*)alloc((size_t)B_*HID_*NE_*2);
  float* wcount= (float*)alloc((size_t)B_*NN_*4);      // contiguous with pooled
  float* pooled= (float*)alloc((size_t)B_*HID_*4);
  float* w1L1  = (float*)alloc((size_t)B_*NN_*4);
  float* f1L1  = (float*)alloc((size_t)B_*NN_*4);
  float* w1L2  = (float*)alloc((size_t)B_*NN_*4);
  float* f1L2  = (float*)alloc((size_t)B_*NN_*4);
  float* f2    = (float*)alloc((size_t)B_*NE_*4);
  float* msum  = (float*)alloc(B_*4);
  float* consts= (float*)alloc(772*4);
  unsigned short* W2T = (unsigned short*)alloc((size_t)HID_*HID_*2);
  if (off > ws_size) return;

  const int kZeroN = B_*NN_ + B_*HID_;    // wcount + pooled

  k_consts<<<9, 128, 0, stream>>>(w2_1, w3_1, a_1, a2_1, wc_1, w2_2, w3_2, a_2, a2_2, wc_2,
                                  w_2, consts, W2T);
  k_zero<<<(kZeroN + 255)/256, 256, 0, stream>>>(wcount, kZeroN);
  k_wcount<<<B_, L_, 0, stream>>>(alias, masks, wcount, msum);
  k_prep<<<dim3(NN_/64, NE_/64, B_), 256, 0, stream>>>(adj, ADJBb, ADJTb);

  // ---------------- layer 1 ----------------
  k_fproj<<<dim3(NN_/64, B_), 256, 0, stream>>>(emb, items, consts, w1L1, f1L1, YT);
  k_gemm_edge<0><<<B_*(NE_/64), 256, 0, stream>>>((const unsigned char*)ADJBb, YT, w1L1,
        consts, 0, W2T, ET, f2);
  k_gemm_att<1><<<B_*(NN_/64), 256, 0, stream>>>((const unsigned char*)ADJTb, ET, f1L1, f2,
        consts, YT, w1L2, f1L2, nullptr, nullptr);

  // ---------------- layer 2 ----------------
  k_gemm_edge<1><<<B_*(NE_/64), 256, 0, stream>>>((const unsigned char*)ADJBb, YT, w1L2,
        consts, 1, W2T, ET, f2);
  k_gemm_att<2><<<B_*(NN_/64), 256, 0, stream>>>((const unsigned char*)ADJTb, ET, f1L2, f2,
        consts, nullptr, nullptr, nullptr, wcount, pooled);

  // ---------------- layernorm ----------------
  k_ln<<<B_, HID_, 0, stream>>>(pooled, msum, ln_g, ln_b, out);
}